// Round 1
// baseline (25321.518 us; speedup 1.0000x reference)
//
#include <hip/hip_runtime.h>
#include <math.h>

#define PP    36864      // H*W = 192*192
#define NCH   128        // C
#define NIN   512        // INNER = HFF

constexpr float ATT_SCALE = 0.125f;            // HID^-0.5
constexpr float LN_EPS    = 1e-5f;
constexpr float PI_F      = 3.14159265358979323846f;

// ---------------- rotary tables: tsin/tcos[192][16] (H==W so one table) ----
__global__ __launch_bounds__(256) void k_rotab(float* __restrict__ ts, float* __restrict__ tc){
    int i = blockIdx.x*256 + threadIdx.x;
    if (i >= 192*16) return;
    int h = i >> 4, j = i & 15;
    float lin = -1.f + 2.f*h/191.f;           // linspace(-1,1,192)
    float sc  = 1.f + 4.f*j/15.f;             // linspace(1,5,16)
    float a   = lin*sc*PI_F;
    ts[i] = sinf(a); tc[i] = cosf(a);
}

// ---------------- channel LayerNorm (NCHW, reduce over C) ------------------
__global__ __launch_bounds__(256) void k_ln(const float* __restrict__ x, const float* __restrict__ g,
                                            const float* __restrict__ b, float* __restrict__ xn){
    int p = blockIdx.x*256 + threadIdx.x;
    float s = 0.f, s2 = 0.f;
    for (int c = 0; c < NCH; ++c){ float v = x[(size_t)c*PP + p]; s += v; s2 += v*v; }
    float mu  = s * (1.f/NCH);
    float var = s2 * (1.f/NCH) - mu*mu;
    float inv = rsqrtf(var + LN_EPS);
    for (int c = 0; c < NCH; ++c){
        float v = x[(size_t)c*PP + p];
        xn[(size_t)c*PP + p] = (v - mu)*inv*g[c] + b[c];
    }
}

// ---------------- GEMM: Out[M][PP] = W[M][K] * X[K][PP] (+bias)(+resid) ----
// 128x128 tile, 256 threads, 8x8 micro-tile. LDS k-major, float4 reads.
__global__ __launch_bounds__(256) void k_gemm(const float* __restrict__ W, const float* __restrict__ X,
                                              float* __restrict__ Out, const float* __restrict__ bias,
                                              const float* __restrict__ resid, int K){
    __shared__ float Wt[64][132];  // [k][m]
    __shared__ float Xt[64][132];  // [k][n]
    int n0 = blockIdx.x*128, m0 = blockIdx.y*128;
    int tid = threadIdx.x;
    int tx = tid & 15, ty = tid >> 4;
    float acc[8][8];
    #pragma unroll
    for (int i=0;i<8;i++)
        #pragma unroll
        for (int j=0;j<8;j++) acc[i][j] = 0.f;

    for (int kc = 0; kc < K; kc += 64){
        // stage W chunk: 128 m x 64 k  (coalesced along K)
        #pragma unroll
        for (int it=0; it<32; ++it){
            int e = tid + 256*it;          // 8192
            int r = e >> 6, c = e & 63;    // r:m-row, c:k-col
            Wt[c][r] = W[(size_t)(m0+r)*K + kc + c];
        }
        // stage X chunk: 64 k x 128 n   (coalesced along N)
        #pragma unroll
        for (int it=0; it<32; ++it){
            int e = tid + 256*it;
            int k = e >> 7, n = e & 127;
            Xt[k][n] = X[(size_t)(kc+k)*PP + n0 + n];
        }
        __syncthreads();
        #pragma unroll 4
        for (int k=0;k<64;k++){
            float4 a0 = *(const float4*)&Wt[k][ty*8];
            float4 a1 = *(const float4*)&Wt[k][ty*8+4];
            float4 b0 = *(const float4*)&Xt[k][tx*4];
            float4 b1 = *(const float4*)&Xt[k][64+tx*4];
            float av[8] = {a0.x,a0.y,a0.z,a0.w,a1.x,a1.y,a1.z,a1.w};
            float bv[8] = {b0.x,b0.y,b0.z,b0.w,b1.x,b1.y,b1.z,b1.w};
            #pragma unroll
            for (int i=0;i<8;i++)
                #pragma unroll
                for (int j=0;j<8;j++) acc[i][j] += av[i]*bv[j];
        }
        __syncthreads();
    }
    #pragma unroll
    for (int i=0;i<8;i++){
        int m = m0 + ty*8 + i;
        float bi = bias ? bias[m] : 0.f;
        #pragma unroll
        for (int g=0; g<2; ++g){
            size_t off = (size_t)m*PP + n0 + g*64 + tx*4;
            float4 v = make_float4(acc[i][g*4+0]+bi, acc[i][g*4+1]+bi,
                                   acc[i][g*4+2]+bi, acc[i][g*4+3]+bi);
            if (resid){
                float4 r4 = *(const float4*)&resid[off];
                v.x+=r4.x; v.y+=r4.y; v.z+=r4.z; v.w+=r4.w;
            }
            *(float4*)&Out[off] = v;
        }
    }
}

// ---------------- rotary (elementwise on flat [r][64] view), float4 --------
__global__ __launch_bounds__(256) void k_rope(float* __restrict__ q, float* __restrict__ k,
                                              const float* __restrict__ ts, const float* __restrict__ tc){
    size_t t = (size_t)blockIdx.x*256 + threadIdx.x;   // over 512*PP/4
    size_t f = t*4;
    int d  = (int)(f & 63);
    int pp = (int)((f >> 6) % PP);
    int hh = pp / 192, ww = pp - hh*192;
    int j  = d & 31;                                    // d%4==0 so all 4 in same half
    int tix = (j < 16) ? (hh*16 + j) : (ww*16 + (j-16));
    float4 s4 = *(const float4*)(ts + tix);
    float4 c4 = *(const float4*)(tc + tix);
    float4 qv = *(float4*)(q + f);
    float4 kv = *(float4*)(k + f);
    // signs per element: even d -> -, odd d -> +   (rot_pairs = [-even, odd])
    qv.x = qv.x*(c4.x - s4.x); qv.y = qv.y*(c4.y + s4.y);
    qv.z = qv.z*(c4.z - s4.z); qv.w = qv.w*(c4.w + s4.w);
    kv.x = kv.x*(1.f - s4.x) + c4.x; kv.y = kv.y*(1.f + s4.y) + c4.y;
    kv.z = kv.z*(1.f - s4.z) + c4.z; kv.w = kv.w*(1.f + s4.w) + c4.w;
    *(float4*)(q + f) = qv;
    *(float4*)(k + f) = kv;
}

// ---------------- window attention (256 rows/window), in-place into q ------
__global__ __launch_bounds__(256) void k_attn(float* __restrict__ q, const float* __restrict__ kb,
                                              const float* __restrict__ vb){
    __shared__ float Ks[64*64];
    __shared__ float Vs[64*64];
    int b = blockIdx.x, i = threadIdx.x;
    size_t base = (size_t)b*16384;                 // window element base (256*64)
    float4 qv[16], ov[16];
    const float4* qp = (const float4*)(q + base + (size_t)i*64);
    #pragma unroll
    for (int t=0;t<16;t++){ qv[t] = qp[t]; ov[t] = make_float4(0.f,0.f,0.f,0.f); }
    float m = -1e30f, l = 0.f;
    #pragma unroll 1
    for (int jc=0;jc<4;jc++){
        if (jc) __syncthreads();
        const float4* ksrc = (const float4*)(kb + base + jc*4096);
        const float4* vsrc = (const float4*)(vb + base + jc*4096);
        #pragma unroll
        for (int t=0;t<4;t++){
            ((float4*)Ks)[i+256*t] = ksrc[i+256*t];
            ((float4*)Vs)[i+256*t] = vsrc[i+256*t];
        }
        __syncthreads();
        #pragma unroll 1
        for (int sb=0; sb<4; ++sb){
            float s[16];
            #pragma unroll
            for (int jj=0;jj<16;jj++){
                const float4* kr = (const float4*)(Ks + (sb*16+jj)*64);
                float a = 0.f;
                #pragma unroll
                for (int t=0;t<16;t++){
                    float4 k4 = kr[t];
                    a += qv[t].x*k4.x + qv[t].y*k4.y + qv[t].z*k4.z + qv[t].w*k4.w;
                }
                s[jj] = a * ATT_SCALE;
            }
            float mx = s[0];
            #pragma unroll
            for (int jj=1;jj<16;jj++) mx = fmaxf(mx, s[jj]);
            float mn = fmaxf(m, mx);
            float corr = __expf(m - mn);
            l *= corr;
            #pragma unroll
            for (int t=0;t<16;t++){ ov[t].x*=corr; ov[t].y*=corr; ov[t].z*=corr; ov[t].w*=corr; }
            #pragma unroll
            for (int jj=0;jj<16;jj++){
                float pe = __expf(s[jj]-mn);
                l += pe;
                const float4* vr = (const float4*)(Vs + (sb*16+jj)*64);
                #pragma unroll
                for (int t=0;t<16;t++){
                    float4 v4 = vr[t];
                    ov[t].x += pe*v4.x; ov[t].y += pe*v4.y; ov[t].z += pe*v4.z; ov[t].w += pe*v4.w;
                }
            }
            m = mn;
        }
    }
    float inv = 1.f / l;
    float4* op = (float4*)(q + base + (size_t)i*64);
    #pragma unroll
    for (int t=0;t<16;t++){
        float4 o4 = ov[t];
        o4.x*=inv; o4.y*=inv; o4.z*=inv; o4.w*=inv;
        op[t] = o4;
    }
}

// ---------------- conv3x3 512->512 SAME + bias + exact GELU ----------------
// block: 64 out-ch x 64 positions (one row segment). 256 thr: ol=tid&63, grp=tid>>6 (16 pos each)
__global__ __launch_bounds__(256) void k_conv(const float* __restrict__ Hin, const float* __restrict__ W2,
                                              const float* __restrict__ b2, float* __restrict__ Hout){
    __shared__ float Wl[64*145];     // [o][c*9+tap], pad 145
    __shared__ float Hl[16*3*68];    // [c][ky][col], pad 68
    int w0 = blockIdx.x*64;
    int h  = blockIdx.y;
    int o0 = blockIdx.z*64;
    int tid = threadIdx.x;
    int ol = tid & 63, grp = tid >> 6;
    float acc[16];
    #pragma unroll
    for (int p=0;p<16;p++) acc[p] = 0.f;

    for (int cc = 0; cc < 512; cc += 16){
        // stage weights: e = o*144 + ct  (coalesced: ct contiguous in global)
        #pragma unroll
        for (int it=0; it<36; ++it){
            int e = tid + 256*it;                 // < 9216
            int o = e / 144, ct = e - o*144;
            Wl[o*145 + ct] = W2[(size_t)(o0+o)*4608 + (size_t)cc*9 + ct];
        }
        // stage H tile: 16c x 3ky x 68col with zero pad
        #pragma unroll
        for (int it=0; it<13; ++it){
            int e = tid + 256*it;
            if (e < 16*3*68){
                int col = e % 68; int t2 = e / 68; int ky = t2 % 3; int c = t2 / 3;
                int hy = h + ky - 1;
                int wx = w0 - 1 + col;
                float v = 0.f;
                if (hy >= 0 && hy < 192 && wx >= 0 && wx < 192)
                    v = Hin[(size_t)(cc+c)*PP + hy*192 + wx];
                Hl[(c*3+ky)*68 + col] = v;
            }
        }
        __syncthreads();
        for (int c=0;c<16;c++){
            #pragma unroll
            for (int ky=0;ky<3;ky++){
                const float4* hr = (const float4*)&Hl[(c*3+ky)*68 + grp*16];
                float hv[20];
                #pragma unroll
                for (int t=0;t<5;t++){ float4 x4 = hr[t]; hv[4*t]=x4.x; hv[4*t+1]=x4.y; hv[4*t+2]=x4.z; hv[4*t+3]=x4.w; }
                #pragma unroll
                for (int kx=0;kx<3;kx++){
                    float wv = Wl[ol*145 + c*9 + ky*3 + kx];
                    #pragma unroll
                    for (int p=0;p<16;p++) acc[p] += wv * hv[p+kx];
                }
            }
        }
        __syncthreads();
    }
    // epilogue: transpose via LDS for coalesced store, + bias + exact GELU
    #pragma unroll
    for (int p=0;p<16;p++) Wl[ol*65 + grp*16 + p] = acc[p];
    __syncthreads();
    #pragma unroll
    for (int it=0; it<16; ++it){
        int e = tid + 256*it;                     // < 4096
        int oo = e >> 6, wl = e & 63;
        float v = Wl[oo*65 + wl] + b2[o0+oo];
        v = v * 0.5f * (1.f + erff(v * 0.70710678118654752f));
        Hout[(size_t)(o0+oo)*PP + h*192 + w0 + wl] = v;
    }
}

// ---------------------------------------------------------------------------
extern "C" void kernel_launch(void* const* d_in, const int* in_sizes, int n_in,
                              void* d_out, int out_size, void* d_ws, size_t ws_size,
                              hipStream_t stream){
    const float* x     = (const float*)d_in[0];
    const float* ln1_g = (const float*)d_in[1];
    const float* ln1_b = (const float*)d_in[2];
    const float* wq    = (const float*)d_in[3];
    const float* wkv   = (const float*)d_in[4];
    const float* wo    = (const float*)d_in[5];
    const float* ln2_g = (const float*)d_in[6];
    const float* ln2_b = (const float*)d_in[7];
    const float* w1    = (const float*)d_in[8];
    const float* b1    = (const float*)d_in[9];
    const float* w2    = (const float*)d_in[10];
    const float* b2    = (const float*)d_in[11];
    const float* w3    = (const float*)d_in[12];
    const float* b3    = (const float*)d_in[13];

    float* xo  = (float*)d_out;                     // running x (residual stream)
    float* ws  = (float*)d_ws;
    float* xn  = ws;                                // 128*PP
    float* qb  = xn  + (size_t)NCH*PP;              // 512*PP  (q -> attn out -> h1)
    float* kvb = qb  + (size_t)NIN*PP;              // 1024*PP (kv -> h2)
    float* tsb = kvb + (size_t)2*NIN*PP;            // 3072
    float* tcb = tsb + 3072;                        // 3072

    hipMemcpyAsync(xo, x, sizeof(float)*(size_t)NCH*PP, hipMemcpyDeviceToDevice, stream);
    k_rotab<<<12, 256, 0, stream>>>(tsb, tcb);

    for (int l = 0; l < 2; ++l){
        // ---- attention branch ----
        k_ln<<<144, 256, 0, stream>>>(xo, ln1_g + l*NCH, ln1_b + l*NCH, xn);
        k_gemm<<<dim3(288,4), 256, 0, stream>>>(wq  + (size_t)l*NIN*NCH,   xn, qb,  nullptr, nullptr, NCH);
        k_gemm<<<dim3(288,8), 256, 0, stream>>>(wkv + (size_t)l*2*NIN*NCH, xn, kvb, nullptr, nullptr, NCH);
        k_rope<<<18432, 256, 0, stream>>>(qb, kvb, tsb, tcb);
        k_attn<<<1152, 256, 0, stream>>>(qb, kvb, kvb + (size_t)NIN*PP);
        k_gemm<<<dim3(288,1), 256, 0, stream>>>(wo + (size_t)l*NCH*NIN, qb, xo, nullptr, xo, NIN);
        // ---- LeFF branch ----
        k_ln<<<144, 256, 0, stream>>>(xo, ln2_g + l*NCH, ln2_b + l*NCH, xn);
        k_gemm<<<dim3(288,4), 256, 0, stream>>>(w1 + (size_t)l*NIN*NCH, xn, qb, b1 + l*NIN, nullptr, NCH);
        k_conv<<<dim3(3,192,8), 256, 0, stream>>>(qb, w2 + (size_t)l*NIN*NIN*9, b2 + l*NIN, kvb);
        k_gemm<<<dim3(288,1), 256, 0, stream>>>(w3 + (size_t)l*NCH*NIN, kvb, xo, b3 + l*NCH, xo, NIN);
    }
}

// Round 3
// 3461.794 us; speedup vs baseline: 7.3146x; 7.3146x over previous
//
#include <hip/hip_runtime.h>
#include <hip/hip_bf16.h>
#include <math.h>

#define PP   36864            // 192*192
#define WIDE 192
#define PWP  194              // padded width
#define HB_BYTES ((size_t)194*194*512*2)

typedef __attribute__((ext_vector_type(8))) short short8;
typedef float f32x4 __attribute__((ext_vector_type(4)));
typedef unsigned short u16;
typedef unsigned int   u32;

constexpr float ATT_SCALE = 0.125f;
constexpr float LN_EPS    = 1e-5f;
constexpr float PI_F      = 3.14159265358979323846f;

__device__ __forceinline__ u16 f2b(float x){
    __hip_bfloat16 h = __float2bfloat16(x);
    return __builtin_bit_cast(u16, h);
}
__device__ __forceinline__ float b2f(u16 u){
    u32 v = ((u32)u) << 16;
    return __builtin_bit_cast(float, v);
}

// ---------------- rotary tables ------------------------------------------
__global__ __launch_bounds__(256) void k_rotab(float* __restrict__ ts, float* __restrict__ tc){
    int i = blockIdx.x*256 + threadIdx.x;
    if (i >= 192*16) return;
    int h = i >> 4, j = i & 15;
    float lin = -1.f + 2.f*h/191.f;
    float sc  = 1.f + 4.f*j/15.f;
    float a   = lin*sc*PI_F;
    ts[i] = sinf(a); tc[i] = cosf(a);
}

// ---------------- fp32 -> bf16 cast --------------------------------------
__global__ __launch_bounds__(256) void k_cast(const float* __restrict__ s, u16* __restrict__ d, int n){
    int i = blockIdx.x*256 + threadIdx.x;
    if (i < n) d[i] = f2b(s[i]);
}

// ---------------- w2 reorder: [o][c][t] -> [t][o][c] bf16 ----------------
__global__ __launch_bounds__(256) void k_w2re(const float* __restrict__ s, u16* __restrict__ d){
    int i = blockIdx.x*256 + threadIdx.x;
    if (i >= 9*512*512) return;
    int t = i >> 18;            // /262144
    int rem = i & 262143;       // o*512 + c
    d[i] = f2b(s[(size_t)rem*9 + t]);
}

// ---------------- channel LayerNorm -> position-major bf16 [p][128] ------
__global__ __launch_bounds__(256) void k_ln(const float* __restrict__ x, const float* __restrict__ g,
                                            const float* __restrict__ b, u32* __restrict__ xt){
    int p = blockIdx.x*256 + threadIdx.x;
    float s = 0.f, s2 = 0.f;
    for (int c = 0; c < 128; ++c){ float v = x[(size_t)c*PP + p]; s += v; s2 += v*v; }
    float mu  = s * (1.f/128.f);
    float var = s2 * (1.f/128.f) - mu*mu;
    float inv = rsqrtf(var + LN_EPS);
    for (int c = 0; c < 64; ++c){
        float v0 = (x[(size_t)(2*c)*PP + p]   - mu)*inv*g[2*c]   + b[2*c];
        float v1 = (x[(size_t)(2*c+1)*PP + p] - mu)*inv*g[2*c+1] + b[2*c+1];
        xt[(size_t)p*64 + c] = (u32)f2b(v0) | ((u32)f2b(v1) << 16);
    }
}

// ---------------- MFMA GEMM: Out[m][n] = sum_k A[m][k] * B[n][k] ----------
// A bf16 [M][K] row-major, B bf16 [N=PP][K] row-major. 128x128 block, 4 waves.
// MODE 0: fp32 out [m][PP] (+bias,+resid)
// MODE 1: bf16 out to padded Hb [(ph+1)*194+pw+1][512] + bias
// MODE 2: m<512 -> fp32 outF [m][PP]; m>=512 -> bf16 outB [(m-512)][PP]
template<int K, int MODE>
__global__ __launch_bounds__(256) void k_mmbt(const u16* __restrict__ A, const u16* __restrict__ B,
        float* __restrict__ outF, u16* __restrict__ outB,
        const float* __restrict__ bias, const float* __restrict__ resid){
    int tid = threadIdx.x;
    int lane = tid & 63, wid = tid >> 6;
    int wm = wid >> 1, wn = wid & 1;
    int n0 = blockIdx.x*128 + wn*64;
    int m0 = blockIdx.y*128 + wm*64;
    int lr = lane & 15, lk = (lane >> 4) * 8;

    f32x4 acc[4][4];
    #pragma unroll
    for (int i=0;i<4;i++)
        #pragma unroll
        for (int j=0;j<4;j++) acc[i][j] = (f32x4){0.f,0.f,0.f,0.f};

    const u16* Ap = A + (size_t)(m0 + lr)*K + lk;
    const u16* Bp = B + (size_t)(n0 + lr)*K + lk;

    #pragma unroll 2
    for (int kc = 0; kc < K; kc += 32){
        short8 af[4], bf[4];
        #pragma unroll
        for (int i=0;i<4;i++) af[i] = *(const short8*)(Ap + (size_t)i*16*K + kc);
        #pragma unroll
        for (int i=0;i<4;i++) bf[i] = *(const short8*)(Bp + (size_t)i*16*K + kc);
        #pragma unroll
        for (int mi=0;mi<4;mi++)
            #pragma unroll
            for (int ni=0;ni<4;ni++)
                acc[mi][ni] = __builtin_amdgcn_mfma_f32_16x16x32_bf16(af[mi], bf[ni], acc[mi][ni], 0,0,0);
    }

    #pragma unroll
    for (int mi=0;mi<4;mi++){
        int mb = m0 + mi*16 + (lane>>4)*4;      // 4 consecutive out rows
        #pragma unroll
        for (int ni=0;ni<4;ni++){
            int n = n0 + ni*16 + lr;
            if (MODE == 0){
                #pragma unroll
                for (int r=0;r<4;r++){
                    int m = mb + r;
                    float v = acc[mi][ni][r];
                    if (bias)  v += bias[m];
                    size_t idx = (size_t)m*PP + n;
                    if (resid) v += resid[idx];
                    outF[idx] = v;
                }
            } else if (MODE == 1){
                int ph = n / 192, pw = n - ph*192;
                size_t ppos = (size_t)(ph+1)*PWP + (pw+1);
                ushort4 st;
                st.x = f2b(acc[mi][ni][0] + bias[mb]);
                st.y = f2b(acc[mi][ni][1] + bias[mb+1]);
                st.z = f2b(acc[mi][ni][2] + bias[mb+2]);
                st.w = f2b(acc[mi][ni][3] + bias[mb+3]);
                *(ushort4*)(outB + ppos*512 + mb) = st;
            } else { // MODE 2
                if (m0 < 512){
                    #pragma unroll
                    for (int r=0;r<4;r++)
                        outF[(size_t)(mb+r)*PP + n] = acc[mi][ni][r];
                } else {
                    #pragma unroll
                    for (int r=0;r<4;r++)
                        outB[(size_t)(mb+r-512)*PP + n] = f2b(acc[mi][ni][r]);
                }
            }
        }
    }
}

// ---------------- rotary (elementwise on flat [r][64] view) ---------------
__global__ __launch_bounds__(256) void k_rope(float* __restrict__ q, float* __restrict__ k,
                                              const float* __restrict__ ts, const float* __restrict__ tc){
    size_t t = (size_t)blockIdx.x*256 + threadIdx.x;
    size_t f = t*4;
    int d  = (int)(f & 63);
    int pp = (int)((f >> 6) % PP);
    int hh = pp / 192, ww = pp - hh*192;
    int j  = d & 31;
    int tix = (j < 16) ? (hh*16 + j) : (ww*16 + (j-16));
    float4 s4 = *(const float4*)(ts + tix);
    float4 c4 = *(const float4*)(tc + tix);
    float4 qv = *(float4*)(q + f);
    float4 kv = *(float4*)(k + f);
    qv.x = qv.x*(c4.x - s4.x); qv.y = qv.y*(c4.y + s4.y);
    qv.z = qv.z*(c4.z - s4.z); qv.w = qv.w*(c4.w + s4.w);
    kv.x = kv.x*(1.f - s4.x) + c4.x; kv.y = kv.y*(1.f + s4.y) + c4.y;
    kv.z = kv.z*(1.f - s4.z) + c4.z; kv.w = kv.w*(1.f + s4.w) + c4.w;
    *(float4*)(q + f) = qv;
    *(float4*)(k + f) = kv;
}

// ---------------- window attention, fp32, V bf16, in-place into q --------
__global__ __launch_bounds__(256) void k_attn(float* __restrict__ q, const float* __restrict__ kb,
                                              const u16* __restrict__ vb){
    __shared__ float Ks[64*64];
    __shared__ float Vs[64*64];
    int b = blockIdx.x, i = threadIdx.x;
    size_t base = (size_t)b*16384;
    float4 qv[16], ov[16];
    const float4* qp = (const float4*)(q + base + (size_t)i*64);
    #pragma unroll
    for (int t=0;t<16;t++){ qv[t] = qp[t]; ov[t] = make_float4(0.f,0.f,0.f,0.f); }
    float m = -1e30f, l = 0.f;
    #pragma unroll 1
    for (int jc=0;jc<4;jc++){
        if (jc) __syncthreads();
        const float4* ksrc = (const float4*)(kb + base + jc*4096);
        const short8* vsrc = (const short8*)(vb + base + jc*4096);
        #pragma unroll
        for (int t=0;t<4;t++) ((float4*)Ks)[i+256*t] = ksrc[i+256*t];
        #pragma unroll
        for (int t=0;t<2;t++){
            short8 vv = vsrc[i+256*t];
            float4 lo, hi;
            lo.x=b2f((u16)vv[0]); lo.y=b2f((u16)vv[1]); lo.z=b2f((u16)vv[2]); lo.w=b2f((u16)vv[3]);
            hi.x=b2f((u16)vv[4]); hi.y=b2f((u16)vv[5]); hi.z=b2f((u16)vv[6]); hi.w=b2f((u16)vv[7]);
            ((float4*)Vs)[(i+256*t)*2]   = lo;
            ((float4*)Vs)[(i+256*t)*2+1] = hi;
        }
        __syncthreads();
        #pragma unroll 1
        for (int sb=0; sb<4; ++sb){
            float s[16];
            #pragma unroll
            for (int jj=0;jj<16;jj++){
                const float4* kr = (const float4*)(Ks + (sb*16+jj)*64);
                float a = 0.f;
                #pragma unroll
                for (int t=0;t<16;t++){
                    float4 k4 = kr[t];
                    a += qv[t].x*k4.x + qv[t].y*k4.y + qv[t].z*k4.z + qv[t].w*k4.w;
                }
                s[jj] = a * ATT_SCALE;
            }
            float mx = s[0];
            #pragma unroll
            for (int jj=1;jj<16;jj++) mx = fmaxf(mx, s[jj]);
            float mn = fmaxf(m, mx);
            float corr = __expf(m - mn);
            l *= corr;
            #pragma unroll
            for (int t=0;t<16;t++){ ov[t].x*=corr; ov[t].y*=corr; ov[t].z*=corr; ov[t].w*=corr; }
            #pragma unroll
            for (int jj=0;jj<16;jj++){
                float pe = __expf(s[jj]-mn);
                l += pe;
                const float4* vr = (const float4*)(Vs + (sb*16+jj)*64);
                #pragma unroll
                for (int t=0;t<16;t++){
                    float4 v4 = vr[t];
                    ov[t].x += pe*v4.x; ov[t].y += pe*v4.y; ov[t].z += pe*v4.z; ov[t].w += pe*v4.w;
                }
            }
            m = mn;
        }
    }
    float inv = 1.f / l;
    float4* op = (float4*)(q + base + (size_t)i*64);
    #pragma unroll
    for (int t=0;t<16;t++){
        float4 o4 = ov[t];
        o4.x*=inv; o4.y*=inv; o4.z*=inv; o4.w*=inv;
        op[t] = o4;
    }
}

// ---------------- transpose: fp32 [512][PP] -> bf16 [PP][512] -------------
__global__ __launch_bounds__(256) void k_tr(const float* __restrict__ in, u16* __restrict__ out){
    __shared__ float T[64][65];
    int p0 = blockIdx.x*64, c0 = blockIdx.y*64;
    int tid = threadIdx.x;
    #pragma unroll
    for (int it=0; it<16; ++it){
        int e = tid + 256*it;          // 4096
        int c = e >> 6, p = e & 63;
        T[c][p] = in[(size_t)(c0+c)*PP + p0 + p];
    }
    __syncthreads();
    #pragma unroll
    for (int it=0; it<4; ++it){
        int e = tid + 256*it;          // 1024
        int p = e >> 4, qd = e & 15;
        ushort4 st;
        st.x = f2b(T[qd*4+0][p]); st.y = f2b(T[qd*4+1][p]);
        st.z = f2b(T[qd*4+2][p]); st.w = f2b(T[qd*4+3][p]);
        *(ushort4*)(out + (size_t)(p0+p)*512 + c0 + qd*4) = st;
    }
}

// ---------------- conv3x3 as 9 shifted MFMA GEMMs, no LDS -----------------
// Wr bf16 [9][512 o][512 c]; Hb bf16 padded [194*194][512]; out Gb bf16 [PP][512] (bias+GELU)
__global__ __launch_bounds__(256) void k_conv(const u16* __restrict__ Wr, const u16* __restrict__ Hb,
                                              const float* __restrict__ b2, u16* __restrict__ Gb){
    int tid = threadIdx.x;
    int lane = tid & 63, wid = tid >> 6;
    int wm = wid >> 1, wn = wid & 1;
    int h = blockIdx.x;
    int o0 = blockIdx.y*128 + wm*64;
    int lr = lane & 15, lk = (lane>>4)*8;
    int colb = wn*96;

    f32x4 acc[4][6];
    #pragma unroll
    for (int i=0;i<4;i++)
        #pragma unroll
        for (int j=0;j<6;j++) acc[i][j] = (f32x4){0.f,0.f,0.f,0.f};

    const u16* Ap = Wr + (size_t)(o0 + lr)*512 + lk;
    const u16* Bp = Hb + lk;

    for (int c0 = 0; c0 < 512; c0 += 32){
        #pragma unroll
        for (int t=0;t<9;t++){
            int ky = t/3, kx = t - ky*3;
            short8 af[4], bf[6];
            #pragma unroll
            for (int mi=0;mi<4;mi++)
                af[mi] = *(const short8*)(Ap + ((size_t)t*512 + mi*16)*512 + c0);
            #pragma unroll
            for (int nj=0;nj<6;nj++){
                int ppos = (h+ky)*PWP + colb + nj*16 + lr + kx;
                bf[nj] = *(const short8*)(Bp + (size_t)ppos*512 + c0);
            }
            #pragma unroll
            for (int mi=0;mi<4;mi++)
                #pragma unroll
                for (int nj=0;nj<6;nj++)
                    acc[mi][nj] = __builtin_amdgcn_mfma_f32_16x16x32_bf16(af[mi], bf[nj], acc[mi][nj], 0,0,0);
        }
    }

    #pragma unroll
    for (int mi=0;mi<4;mi++){
        int ob = o0 + mi*16 + (lane>>4)*4;
        float b0 = b2[ob], b1v = b2[ob+1], b2v = b2[ob+2], b3v = b2[ob+3];
        #pragma unroll
        for (int nj=0;nj<6;nj++){
            int p = h*192 + colb + nj*16 + lr;
            float v[4] = {acc[mi][nj][0]+b0, acc[mi][nj][1]+b1v, acc[mi][nj][2]+b2v, acc[mi][nj][3]+b3v};
            ushort4 st;
            #pragma unroll
            for (int r=0;r<4;r++){
                float g = v[r]*0.5f*(1.f + erff(v[r]*0.70710678118654752f));
                ((u16*)&st)[r] = f2b(g);
            }
            *(ushort4*)(Gb + (size_t)p*512 + ob) = st;
        }
    }
}

// ---------------------------------------------------------------------------
extern "C" void kernel_launch(void* const* d_in, const int* in_sizes, int n_in,
                              void* d_out, int out_size, void* d_ws, size_t ws_size,
                              hipStream_t stream){
    const float* x     = (const float*)d_in[0];
    const float* ln1_g = (const float*)d_in[1];
    const float* ln1_b = (const float*)d_in[2];
    const float* wq    = (const float*)d_in[3];
    const float* wkv   = (const float*)d_in[4];
    const float* wo    = (const float*)d_in[5];
    const float* ln2_g = (const float*)d_in[6];
    const float* ln2_b = (const float*)d_in[7];
    const float* w1    = (const float*)d_in[8];
    const float* b1    = (const float*)d_in[9];
    const float* w2    = (const float*)d_in[10];
    const float* b2    = (const float*)d_in[11];
    const float* w3    = (const float*)d_in[12];
    const float* b3    = (const float*)d_in[13];

    float* xo = (float*)d_out;
    char* base = (char*)d_ws;

    // R1 region: xn_t (bf16 [PP][128]) / at_t (bf16 [PP][512]) / Gb (bf16 [PP][512])
    u16*  R1   = (u16*)(base);
    float* q   = (float*)(base + 37748736);          // fp32 [512][PP]; Hb overlays here
    u16*  Hb   = (u16*)(base + 37748736);            // padded bf16 [194*194][512]
    float* kbuf= (float*)(base + 113246208);         // fp32 [512][PP]
    u16*  vbf  = (u16*)(base + 188743680);           // bf16 [512][PP]
    u16*  wqb  = (u16*)(base + 226492416);
    u16*  wkvb = (u16*)(base + 226754560);
    u16*  wob  = (u16*)(base + 227278848);
    u16*  w1b  = (u16*)(base + 227540992);
    u16*  w3b  = (u16*)(base + 227803136);
    u16*  w2r  = (u16*)(base + 228065280);           // 2 * 9*512*512
    float* tsb = (float*)(base + 237502464);
    float* tcb = (float*)(base + 237514752);

    (void)hipMemcpyAsync(xo, x, sizeof(float)*(size_t)128*PP, hipMemcpyDeviceToDevice, stream);
    k_rotab<<<12, 256, 0, stream>>>(tsb, tcb);
    k_cast<<<512,  256, 0, stream>>>(wq,  wqb,  131072);
    k_cast<<<1024, 256, 0, stream>>>(wkv, wkvb, 262144);
    k_cast<<<512,  256, 0, stream>>>(wo,  wob,  131072);
    k_cast<<<512,  256, 0, stream>>>(w1,  w1b,  131072);
    k_cast<<<512,  256, 0, stream>>>(w3,  w3b,  131072);
    for (int l=0;l<2;l++)
        k_w2re<<<9216, 256, 0, stream>>>(w2 + (size_t)l*2359296, w2r + (size_t)l*2359296);

    for (int l = 0; l < 2; ++l){
        // ---- attention branch ----
        k_ln<<<144, 256, 0, stream>>>(xo, ln1_g + l*128, ln1_b + l*128, (u32*)R1);
        k_mmbt<128,0><<<dim3(288,4), 256, 0, stream>>>(wqb + (size_t)l*65536, R1, q, nullptr, nullptr, nullptr);
        k_mmbt<128,2><<<dim3(288,8), 256, 0, stream>>>(wkvb + (size_t)l*131072, R1, kbuf, vbf, nullptr, nullptr);
        k_rope<<<18432, 256, 0, stream>>>(q, kbuf, tsb, tcb);
        k_attn<<<1152, 256, 0, stream>>>(q, kbuf, vbf);
        k_tr<<<dim3(576,8), 256, 0, stream>>>(q, R1);
        k_mmbt<512,0><<<dim3(288,1), 256, 0, stream>>>(wob + (size_t)l*65536, R1, xo, nullptr, nullptr, xo);
        // ---- LeFF branch ----
        k_ln<<<144, 256, 0, stream>>>(xo, ln2_g + l*128, ln2_b + l*128, (u32*)R1);
        (void)hipMemsetAsync(Hb, 0, HB_BYTES, stream);
        k_mmbt<128,1><<<dim3(288,4), 256, 0, stream>>>(w1b + (size_t)l*65536, R1, nullptr, Hb, b1 + l*512, nullptr);
        k_conv<<<dim3(192,4), 256, 0, stream>>>(w2r + (size_t)l*2359296, Hb, b2 + l*512, R1);
        k_mmbt<512,0><<<dim3(288,1), 256, 0, stream>>>(w3b + (size_t)l*65536, R1, xo, nullptr, b3 + l*128, xo);
    }
}

// Round 4
// 2041.230 us; speedup vs baseline: 12.4050x; 1.6959x over previous
//
#include <hip/hip_runtime.h>
#include <hip/hip_bf16.h>
#include <math.h>

#define PP   36864            // 192*192
#define PWP  194              // padded width
#define HB_BYTES ((size_t)194*194*512*2)

typedef __attribute__((ext_vector_type(8))) short short8;
typedef float f32x4 __attribute__((ext_vector_type(4)));
typedef unsigned short u16;
typedef unsigned int   u32;

constexpr float LN_EPS = 1e-5f;
constexpr float PI_F   = 3.14159265358979323846f;

__device__ __forceinline__ u16 f2b(float x){
    __hip_bfloat16 h = __float2bfloat16(x);
    return __builtin_bit_cast(u16, h);
}
__device__ __forceinline__ float b2f(u16 u){
    u32 v = ((u32)u) << 16;
    return __builtin_bit_cast(float, v);
}

// ---------------- rotary tables ------------------------------------------
__global__ __launch_bounds__(256) void k_rotab(float* __restrict__ ts, float* __restrict__ tc){
    int i = blockIdx.x*256 + threadIdx.x;
    if (i >= 192*16) return;
    int h = i >> 4, j = i & 15;
    float lin = -1.f + 2.f*h/191.f;
    float sc  = 1.f + 4.f*j/15.f;
    float a   = lin*sc*PI_F;
    ts[i] = sinf(a); tc[i] = cosf(a);
}

// ---------------- fp32 -> bf16 cast --------------------------------------
__global__ __launch_bounds__(256) void k_cast(const float* __restrict__ s, u16* __restrict__ d, int n){
    int i = blockIdx.x*256 + threadIdx.x;
    if (i < n) d[i] = f2b(s[i]);
}

// ---------------- w2 reorder: [o][c][t] -> [t][o][c] bf16 ----------------
__global__ __launch_bounds__(256) void k_w2re(const float* __restrict__ s, u16* __restrict__ d){
    int i = blockIdx.x*256 + threadIdx.x;
    if (i >= 9*512*512) return;
    int t = i >> 18;
    int rem = i & 262143;       // o*512 + c
    d[i] = f2b(s[(size_t)rem*9 + t]);
}

// ---------------- channel LayerNorm -> position-major bf16 [p][128] ------
__global__ __launch_bounds__(256) void k_ln(const float* __restrict__ x, const float* __restrict__ g,
                                            const float* __restrict__ b, u32* __restrict__ xt){
    int p = blockIdx.x*256 + threadIdx.x;
    float s = 0.f, s2 = 0.f;
    for (int c = 0; c < 128; ++c){ float v = x[(size_t)c*PP + p]; s += v; s2 += v*v; }
    float mu  = s * (1.f/128.f);
    float var = s2 * (1.f/128.f) - mu*mu;
    float inv = rsqrtf(var + LN_EPS);
    for (int c = 0; c < 64; ++c){
        float v0 = (x[(size_t)(2*c)*PP + p]   - mu)*inv*g[2*c]   + b[2*c];
        float v1 = (x[(size_t)(2*c+1)*PP + p] - mu)*inv*g[2*c+1] + b[2*c+1];
        xt[(size_t)p*64 + c] = (u32)f2b(v0) | ((u32)f2b(v1) << 16);
    }
}

// ---------------- MFMA GEMM: Out[m][n] = sum_k A[m][k] * B[n][k] ----------
// A bf16 [M][K] row-major, B bf16 [N=PP][K] row-major. 128x128 block, 4 waves.
// MODE 0: fp32 out [m][PP] (+bias,+resid)
// MODE 1: bf16 out to padded Hb [(ph+1)*194+pw+1][512] + bias
// MODE 3: rope-q: outB u16 flat[m*PP+n] = bf16( a*(cos+-sin)*0.125 )
// MODE 4: m<512: rope-k -> outB; m>=512: plain bf16 -> outB2[(m-512)*PP+n]
template<int K, int MODE>
__global__ __launch_bounds__(256) void k_mmbt(const u16* __restrict__ A, const u16* __restrict__ B,
        float* __restrict__ outF, u16* __restrict__ outB, u16* __restrict__ outB2,
        const float* __restrict__ bias, const float* __restrict__ resid,
        const float* __restrict__ ts, const float* __restrict__ tc){
    int tid = threadIdx.x;
    int lane = tid & 63, wid = tid >> 6;
    int wm = wid >> 1, wn = wid & 1;
    int n0 = blockIdx.x*128 + wn*64;
    int m0 = blockIdx.y*128 + wm*64;
    int lr = lane & 15, lk = (lane >> 4) * 8;

    f32x4 acc[4][4];
    #pragma unroll
    for (int i=0;i<4;i++)
        #pragma unroll
        for (int j=0;j<4;j++) acc[i][j] = (f32x4){0.f,0.f,0.f,0.f};

    const u16* Ap = A + (size_t)(m0 + lr)*K + lk;
    const u16* Bp = B + (size_t)(n0 + lr)*K + lk;

    #pragma unroll 2
    for (int kc = 0; kc < K; kc += 32){
        short8 af[4], bf[4];
        #pragma unroll
        for (int i=0;i<4;i++) af[i] = *(const short8*)(Ap + (size_t)i*16*K + kc);
        #pragma unroll
        for (int i=0;i<4;i++) bf[i] = *(const short8*)(Bp + (size_t)i*16*K + kc);
        #pragma unroll
        for (int mi=0;mi<4;mi++)
            #pragma unroll
            for (int ni=0;ni<4;ni++)
                acc[mi][ni] = __builtin_amdgcn_mfma_f32_16x16x32_bf16(af[mi], bf[ni], acc[mi][ni], 0,0,0);
    }

    #pragma unroll
    for (int mi=0;mi<4;mi++){
        int mb = m0 + mi*16 + (lane>>4)*4;
        #pragma unroll
        for (int ni=0;ni<4;ni++){
            int n = n0 + ni*16 + lr;
            if (MODE == 0){
                #pragma unroll
                for (int r=0;r<4;r++){
                    int m = mb + r;
                    float v = acc[mi][ni][r];
                    if (bias)  v += bias[m];
                    size_t idx = (size_t)m*PP + n;
                    if (resid) v += resid[idx];
                    outF[idx] = v;
                }
            } else if (MODE == 1){
                int ph = n / 192, pw = n - ph*192;
                size_t ppos = (size_t)(ph+1)*PWP + (pw+1);
                ushort4 st;
                st.x = f2b(acc[mi][ni][0] + bias[mb]);
                st.y = f2b(acc[mi][ni][1] + bias[mb+1]);
                st.z = f2b(acc[mi][ni][2] + bias[mb+2]);
                st.w = f2b(acc[mi][ni][3] + bias[mb+3]);
                *(ushort4*)(outB + ppos*512 + mb) = st;
            } else { // MODE 3 / 4 : rope fused
                int d = n & 63, j = d & 31;
                int nb6 = n >> 6;
                #pragma unroll
                for (int r=0;r<4;r++){
                    int m = mb + r;
                    float a = acc[mi][ni][r];
                    if (MODE == 4 && m >= 512){
                        outB2[(size_t)(m-512)*PP + n] = f2b(a);
                    } else {
                        int pp = (m & 63)*576 + nb6;
                        int h = pp / 192, w = pp - h*192;
                        int tix = (j < 16) ? (h*16 + j) : (w*16 + (j-16));
                        float sv = ts[tix], cv = tc[tix];
                        float sg = (d & 1) ? sv : -sv;
                        float val;
                        if (MODE == 3) val = a * (cv + sg) * 0.125f;
                        else           val = a * (1.f + sg) + cv;
                        outB[(size_t)m*PP + n] = f2b(val);
                    }
                }
            }
        }
    }
}

// ---------------- V window transpose: vbf flat [row][64] -> vt [win][d][j] --
__global__ __launch_bounds__(256) void k_vt(const u16* __restrict__ v, u16* __restrict__ vt){
    __shared__ u32 TI[64][132];
    int tid = threadIdx.x;
    size_t wbase = (size_t)blockIdx.x*16384;
    int jp = tid >> 1, half = tid & 1;
    const u16* r0 = v + wbase + (size_t)(2*jp)*64 + half*32;
    const u16* r1 = r0 + 64;
    #pragma unroll
    for (int t=0; t<4; t++){
        short8 a = *(const short8*)(r0 + t*8);
        short8 b = *(const short8*)(r1 + t*8);
        #pragma unroll
        for (int e=0; e<8; e++){
            int d = half*32 + t*8 + e;
            TI[d][jp] = (u32)(u16)a[e] | ((u32)(u16)b[e] << 16);
        }
    }
    __syncthreads();
    int d = tid >> 2, q4 = tid & 3;
    u32* o32 = (u32*)(vt + wbase) + d*128 + q4*32;
    #pragma unroll
    for (int t=0; t<32; t++) o32[t] = TI[d][q4*32 + t];
}

// ---------------- MFMA flash window-attention -----------------------------
// q16: rope'd+scaled Q bf16 flat [row][64]; k16: rope'd K; vt: [win][d][j]
// out ob bf16 flat [row][64]. 1 block = 1 window (256 rows), 4 waves x 64 rows.
__global__ __launch_bounds__(256,2) void k_attn(const u16* __restrict__ q16, const u16* __restrict__ k16,
                                                const u16* __restrict__ vt, u16* __restrict__ ob){
    __shared__ u16 Pt[4][64][80];     // per-wave P^T [i][j], row=160B (16B aligned)
    __shared__ float bc[4][64];       // per-wave broadcast (corr / 1/l)
    int tid = threadIdx.x;
    int wave = tid >> 6, lane = tid & 63;
    int lr = lane & 15, g = lane >> 4;
    int lk = g*8;
    size_t wbase = (size_t)blockIdx.x * 16384;

    // hoist Q B-frags (wave's own 64 rows)
    short8 bq[2][4];
    #pragma unroll
    for (int kh=0; kh<2; kh++)
        #pragma unroll
        for (int ni=0; ni<4; ni++)
            bq[kh][ni] = *(const short8*)(q16 + wbase + (size_t)(wave*64 + ni*16 + lr)*64 + kh*32 + lk);

    f32x4 oAcc[4][4];
    #pragma unroll
    for (int mi=0;mi<4;mi++)
        #pragma unroll
        for (int ni=0;ni<4;ni++) oAcc[mi][ni] = (f32x4){0.f,0.f,0.f,0.f};
    float mrun[4], lrun[4];
    #pragma unroll
    for (int ni=0;ni<4;ni++){ mrun[ni] = -1e30f; lrun[ni] = 0.f; }

    #pragma unroll 1
    for (int jc=0; jc<4; ++jc){
        // S^T = K . Q^T : lane holds S^T[j = jc*64+mi*16+g*4+r][i = wave*64+ni*16+lr]
        f32x4 sAcc[4][4];
        #pragma unroll
        for (int mi=0;mi<4;mi++)
            #pragma unroll
            for (int ni=0;ni<4;ni++) sAcc[mi][ni] = (f32x4){0.f,0.f,0.f,0.f};
        #pragma unroll
        for (int kh=0; kh<2; kh++){
            short8 ak[4];
            #pragma unroll
            for (int mi=0;mi<4;mi++)
                ak[mi] = *(const short8*)(k16 + wbase + (size_t)(jc*64 + mi*16 + lr)*64 + kh*32 + lk);
            #pragma unroll
            for (int mi=0;mi<4;mi++)
                #pragma unroll
                for (int ni=0;ni<4;ni++)
                    sAcc[mi][ni] = __builtin_amdgcn_mfma_f32_16x16x32_bf16(ak[mi], bq[kh][ni], sAcc[mi][ni], 0,0,0);
        }
        // online softmax over j (rows of S^T): in-lane (mi,r) + cross-g shfl
        float corr[4];
        #pragma unroll
        for (int ni=0;ni<4;ni++){
            float mx = sAcc[0][ni][0];
            #pragma unroll
            for (int mi=0;mi<4;mi++)
                #pragma unroll
                for (int r=0;r<4;r++) mx = fmaxf(mx, sAcc[mi][ni][r]);
            mx = fmaxf(mx, __shfl_xor(mx, 16));
            mx = fmaxf(mx, __shfl_xor(mx, 32));
            float mnew = fmaxf(mrun[ni], mx);
            corr[ni] = __expf(mrun[ni] - mnew);
            mrun[ni] = mnew;
        }
        #pragma unroll
        for (int ni=0;ni<4;ni++){
            float ls = 0.f;
            #pragma unroll
            for (int mi=0;mi<4;mi++)
                #pragma unroll
                for (int r=0;r<4;r++){
                    float p = __expf(sAcc[mi][ni][r] - mrun[ni]);
                    sAcc[mi][ni][r] = p;
                    ls += p;
                }
            ls += __shfl_xor(ls, 16);
            ls += __shfl_xor(ls, 32);
            lrun[ni] = lrun[ni]*corr[ni] + ls;
        }
        // broadcast corr by row-i, rescale O (O rows are mi*16+g*4+r)
        if (lane < 16){
            #pragma unroll
            for (int ni=0;ni<4;ni++) bc[wave][ni*16 + lr] = corr[ni];
        }
        #pragma unroll
        for (int mi=0;mi<4;mi++){
            float4 cf = *(float4*)&bc[wave][mi*16 + g*4];
            #pragma unroll
            for (int ni=0;ni<4;ni++){
                oAcc[mi][ni][0] *= cf.x; oAcc[mi][ni][1] *= cf.y;
                oAcc[mi][ni][2] *= cf.z; oAcc[mi][ni][3] *= cf.w;
            }
        }
        // pack P^T -> Pt: element (j=mi*16+g*4+r, i=ni*16+lr); r consecutive -> b64
        #pragma unroll
        for (int mi=0;mi<4;mi++)
            #pragma unroll
            for (int ni=0;ni<4;ni++){
                ushort4 pk;
                pk.x = f2b(sAcc[mi][ni][0]); pk.y = f2b(sAcc[mi][ni][1]);
                pk.z = f2b(sAcc[mi][ni][2]); pk.w = f2b(sAcc[mi][ni][3]);
                *(ushort4*)&Pt[wave][ni*16 + lr][mi*16 + g*4] = pk;
            }
        // PV: A = P (rows i from Pt), B = V^T rows d (global vt)
        #pragma unroll
        for (int kh=0; kh<2; kh++){
            short8 pa[4], bv[4];
            #pragma unroll
            for (int mi=0;mi<4;mi++)
                pa[mi] = *(const short8*)&Pt[wave][mi*16 + lr][kh*32 + lk];
            #pragma unroll
            for (int ni=0;ni<4;ni++)
                bv[ni] = *(const short8*)(vt + wbase + (size_t)(ni*16 + lr)*256 + jc*64 + kh*32 + lk);
            #pragma unroll
            for (int mi=0;mi<4;mi++)
                #pragma unroll
                for (int ni=0;ni<4;ni++)
                    oAcc[mi][ni] = __builtin_amdgcn_mfma_f32_16x16x32_bf16(pa[mi], bv[ni], oAcc[mi][ni], 0,0,0);
        }
    }
    // finalize: broadcast 1/l by row, write O bf16
    if (lane < 16){
        #pragma unroll
        for (int ni=0;ni<4;ni++) bc[wave][ni*16 + lr] = 1.f / lrun[ni];
    }
    #pragma unroll
    for (int mi=0;mi<4;mi++){
        float4 lf = *(float4*)&bc[wave][mi*16 + g*4];
        float lfa[4] = {lf.x, lf.y, lf.z, lf.w};
        #pragma unroll
        for (int ni=0;ni<4;ni++){
            #pragma unroll
            for (int r=0;r<4;r++){
                size_t idx = wbase + (size_t)(wave*64 + mi*16 + g*4 + r)*64 + ni*16 + lr;
                ob[idx] = f2b(oAcc[mi][ni][r] * lfa[r]);
            }
        }
    }
}

// ---------------- transpose: bf16 flat [512][PP] -> bf16 [PP][512] --------
__global__ __launch_bounds__(256) void k_tr(const u16* __restrict__ in, u16* __restrict__ out){
    __shared__ float T[64][65];
    int p0 = blockIdx.x*64, c0 = blockIdx.y*64;
    int tid = threadIdx.x;
    #pragma unroll
    for (int it=0; it<16; ++it){
        int e = tid + 256*it;
        int c = e >> 6, p = e & 63;
        T[c][p] = b2f(in[(size_t)(c0+c)*PP + p0 + p]);
    }
    __syncthreads();
    #pragma unroll
    for (int it=0; it<4; ++it){
        int e = tid + 256*it;
        int p = e >> 4, qd = e & 15;
        ushort4 st;
        st.x = f2b(T[qd*4+0][p]); st.y = f2b(T[qd*4+1][p]);
        st.z = f2b(T[qd*4+2][p]); st.w = f2b(T[qd*4+3][p]);
        *(ushort4*)(out + (size_t)(p0+p)*512 + c0 + qd*4) = st;
    }
}

// ---------------- conv3x3 as 9 shifted MFMA GEMMs, no LDS -----------------
__global__ __launch_bounds__(256) void k_conv(const u16* __restrict__ Wr, const u16* __restrict__ Hb,
                                              const float* __restrict__ b2, u16* __restrict__ Gb){
    int tid = threadIdx.x;
    int lane = tid & 63, wid = tid >> 6;
    int wm = wid >> 1, wn = wid & 1;
    int h = blockIdx.x;
    int o0 = blockIdx.y*128 + wm*64;
    int lr = lane & 15, lk = (lane>>4)*8;
    int colb = wn*96;

    f32x4 acc[4][6];
    #pragma unroll
    for (int i=0;i<4;i++)
        #pragma unroll
        for (int j=0;j<6;j++) acc[i][j] = (f32x4){0.f,0.f,0.f,0.f};

    const u16* Ap = Wr + (size_t)(o0 + lr)*512 + lk;
    const u16* Bp = Hb + lk;

    for (int c0 = 0; c0 < 512; c0 += 32){
        #pragma unroll
        for (int t=0;t<9;t++){
            int ky = t/3, kx = t - ky*3;
            short8 af[4], bf[6];
            #pragma unroll
            for (int mi=0;mi<4;mi++)
                af[mi] = *(const short8*)(Ap + ((size_t)t*512 + mi*16)*512 + c0);
            #pragma unroll
            for (int nj=0;nj<6;nj++){
                int ppos = (h+ky)*PWP + colb + nj*16 + lr + kx;
                bf[nj] = *(const short8*)(Bp + (size_t)ppos*512 + c0);
            }
            #pragma unroll
            for (int mi=0;mi<4;mi++)
                #pragma unroll
                for (int nj=0;nj<6;nj++)
                    acc[mi][nj] = __builtin_amdgcn_mfma_f32_16x16x32_bf16(af[mi], bf[nj], acc[mi][nj], 0,0,0);
        }
    }

    #pragma unroll
    for (int mi=0;mi<4;mi++){
        int ob = o0 + mi*16 + (lane>>4)*4;
        float b0 = b2[ob], b1v = b2[ob+1], b2v = b2[ob+2], b3v = b2[ob+3];
        #pragma unroll
        for (int nj=0;nj<6;nj++){
            int p = h*192 + colb + nj*16 + lr;
            float v[4] = {acc[mi][nj][0]+b0, acc[mi][nj][1]+b1v, acc[mi][nj][2]+b2v, acc[mi][nj][3]+b3v};
            ushort4 st;
            #pragma unroll
            for (int r=0;r<4;r++){
                float gg = v[r]*0.5f*(1.f + erff(v[r]*0.70710678118654752f));
                ((u16*)&st)[r] = f2b(gg);
            }
            *(ushort4*)(Gb + (size_t)p*512 + ob) = st;
        }
    }
}

// ---------------------------------------------------------------------------
extern "C" void kernel_launch(void* const* d_in, const int* in_sizes, int n_in,
                              void* d_out, int out_size, void* d_ws, size_t ws_size,
                              hipStream_t stream){
    const float* x     = (const float*)d_in[0];
    const float* ln1_g = (const float*)d_in[1];
    const float* ln1_b = (const float*)d_in[2];
    const float* wq    = (const float*)d_in[3];
    const float* wkv   = (const float*)d_in[4];
    const float* wo    = (const float*)d_in[5];
    const float* ln2_g = (const float*)d_in[6];
    const float* ln2_b = (const float*)d_in[7];
    const float* w1    = (const float*)d_in[8];
    const float* b1    = (const float*)d_in[9];
    const float* w2    = (const float*)d_in[10];
    const float* b2    = (const float*)d_in[11];
    const float* w3    = (const float*)d_in[12];
    const float* b3    = (const float*)d_in[13];

    float* xo = (float*)d_out;
    char* base = (char*)d_ws;

    u16*  R1   = (u16*)(base);                      //  37,748,736 (xn / attn-out-T / conv Gb consumer)
    u16*  q16  = (u16*)(base + 37748736);           //  bf16 flat q (Hb overlays q16+k16 in LeFF)
    u16*  Hb   = (u16*)(base + 37748736);
    u16*  k16  = (u16*)(base + 75497472);
    u16*  vbf  = (u16*)(base + 113246208);          //  v channel-major; attn O reuses
    u16*  vt   = (u16*)(base + 150994944);          //  V^T per window; conv Gb reuses
    u16*  Gb   = vt;
    u16*  wqb  = (u16*)(base + 188743680);
    u16*  wkvb = (u16*)(base + 189005824);
    u16*  wob  = (u16*)(base + 189530112);
    u16*  w1b  = (u16*)(base + 189792256);
    u16*  w3b  = (u16*)(base + 190054400);
    u16*  w2r  = (u16*)(base + 190316544);          //  2 * 9*512*512
    float* tsb = (float*)(base + 199753728);
    float* tcb = (float*)(base + 199766016);

    (void)hipMemcpyAsync(xo, x, sizeof(float)*(size_t)128*PP, hipMemcpyDeviceToDevice, stream);
    k_rotab<<<12, 256, 0, stream>>>(tsb, tcb);
    k_cast<<<512,  256, 0, stream>>>(wq,  wqb,  131072);
    k_cast<<<1024, 256, 0, stream>>>(wkv, wkvb, 262144);
    k_cast<<<512,  256, 0, stream>>>(wo,  wob,  131072);
    k_cast<<<512,  256, 0, stream>>>(w1,  w1b,  131072);
    k_cast<<<512,  256, 0, stream>>>(w3,  w3b,  131072);
    for (int l=0;l<2;l++)
        k_w2re<<<9216, 256, 0, stream>>>(w2 + (size_t)l*2359296, w2r + (size_t)l*2359296);

    for (int l = 0; l < 2; ++l){
        // ---- attention branch ----
        k_ln<<<144, 256, 0, stream>>>(xo, ln1_g + l*128, ln1_b + l*128, (u32*)R1);
        k_mmbt<128,3><<<dim3(288,4), 256, 0, stream>>>(wqb + (size_t)l*65536, R1,
                nullptr, q16, nullptr, nullptr, nullptr, tsb, tcb);
        k_mmbt<128,4><<<dim3(288,8), 256, 0, stream>>>(wkvb + (size_t)l*131072, R1,
                nullptr, k16, vbf, nullptr, nullptr, tsb, tcb);
        k_vt<<<1152, 256, 0, stream>>>(vbf, vt);
        k_attn<<<1152, 256, 0, stream>>>(q16, k16, vt, vbf);
        k_tr<<<dim3(576,8), 256, 0, stream>>>(vbf, R1);
        k_mmbt<512,0><<<dim3(288,1), 256, 0, stream>>>(wob + (size_t)l*65536, R1,
                xo, nullptr, nullptr, nullptr, xo, nullptr, nullptr);
        // ---- LeFF branch ----
        k_ln<<<144, 256, 0, stream>>>(xo, ln2_g + l*128, ln2_b + l*128, (u32*)R1);
        (void)hipMemsetAsync(Hb, 0, HB_BYTES, stream);
        k_mmbt<128,1><<<dim3(288,4), 256, 0, stream>>>(w1b + (size_t)l*65536, R1,
                nullptr, Hb, nullptr, b1 + l*512, nullptr, nullptr, nullptr);
        k_conv<<<dim3(192,4), 256, 0, stream>>>(w2r + (size_t)l*2359296, Hb, b2 + l*512, Gb);
        k_mmbt<512,0><<<dim3(288,1), 256, 0, stream>>>(w3b + (size_t)l*65536, Gb,
                xo, nullptr, nullptr, b3 + l*128, xo, nullptr, nullptr);
    }
}

// Round 5
// 1489.402 us; speedup vs baseline: 17.0011x; 1.3705x over previous
//
#include <hip/hip_runtime.h>
#include <hip/hip_bf16.h>
#include <math.h>

#define PP   36864            // 192*192
#define PWP  194              // padded width
#define HB_BYTES ((size_t)194*194*512*2)
#define LCOLS 208             // staged cols per ky row (16-aligned, >=194)

typedef __attribute__((ext_vector_type(8))) short short8;
typedef float f32x4 __attribute__((ext_vector_type(4)));
typedef unsigned short u16;
typedef unsigned int   u32;

constexpr float LN_EPS = 1e-5f;
constexpr float PI_F   = 3.14159265358979323846f;

__device__ __forceinline__ u16 f2b(float x){
    __hip_bfloat16 h = __float2bfloat16(x);
    return __builtin_bit_cast(u16, h);
}
__device__ __forceinline__ float b2f(u16 u){
    u32 v = ((u32)u) << 16;
    return __builtin_bit_cast(float, v);
}
__device__ __forceinline__ void stage16(const u16* g, u16* l){
    __builtin_amdgcn_global_load_lds((const __attribute__((address_space(1))) void*)g,
                                     (__attribute__((address_space(3))) void*)l, 16, 0, 0);
}

// ---------------- rotary tables ------------------------------------------
__global__ __launch_bounds__(256) void k_rotab(float* __restrict__ ts, float* __restrict__ tc){
    int i = blockIdx.x*256 + threadIdx.x;
    if (i >= 192*16) return;
    int h = i >> 4, j = i & 15;
    float lin = -1.f + 2.f*h/191.f;
    float sc  = 1.f + 4.f*j/15.f;
    float a   = lin*sc*PI_F;
    ts[i] = sinf(a); tc[i] = cosf(a);
}

// ---------------- fp32 -> bf16 cast --------------------------------------
__global__ __launch_bounds__(256) void k_cast(const float* __restrict__ s, u16* __restrict__ d, int n){
    int i = blockIdx.x*256 + threadIdx.x;
    if (i < n) d[i] = f2b(s[i]);
}

// ---------------- w2 reorder: [o][c][t] -> [t][o][c] bf16 ----------------
__global__ __launch_bounds__(256) void k_w2re(const float* __restrict__ s, u16* __restrict__ d){
    int i = blockIdx.x*256 + threadIdx.x;
    if (i >= 9*512*512) return;
    int t = i >> 18;
    int rem = i & 262143;       // o*512 + c
    d[i] = f2b(s[(size_t)rem*9 + t]);
}

// ---------------- channel LayerNorm -> position-major bf16 [p][128] ------
__global__ __launch_bounds__(256) void k_ln(const float* __restrict__ x, const float* __restrict__ g,
                                            const float* __restrict__ b, u32* __restrict__ xt){
    int p = blockIdx.x*256 + threadIdx.x;
    float s = 0.f, s2 = 0.f;
    for (int c = 0; c < 128; ++c){ float v = x[(size_t)c*PP + p]; s += v; s2 += v*v; }
    float mu  = s * (1.f/128.f);
    float var = s2 * (1.f/128.f) - mu*mu;
    float inv = rsqrtf(var + LN_EPS);
    for (int c = 0; c < 64; ++c){
        float v0 = (x[(size_t)(2*c)*PP + p]   - mu)*inv*g[2*c]   + b[2*c];
        float v1 = (x[(size_t)(2*c+1)*PP + p] - mu)*inv*g[2*c+1] + b[2*c+1];
        xt[(size_t)p*64 + c] = (u32)f2b(v0) | ((u32)f2b(v1) << 16);
    }
}

// ---------------- MFMA GEMM: Out[m][n] = sum_k A[m][k] * B[n][k] ----------
// A bf16 [M][K] row-major, B bf16 [N=PP][K] row-major. 128x128 block, 4 waves.
// MODE 0: fp32 out [m][PP] (+bias,+resid)
// MODE 1: bf16 out to padded Hb [(ph+1)*194+pw+1][512] + bias
// MODE 3: rope-q: outB u16 flat[m*PP+n] = bf16( a*(cos+-sin)*0.125 )
// MODE 4: m<512: rope-k -> outB; m>=512: plain bf16 -> outB2[(m-512)*PP+n]
template<int K, int MODE>
__global__ __launch_bounds__(256) void k_mmbt(const u16* __restrict__ A, const u16* __restrict__ B,
        float* __restrict__ outF, u16* __restrict__ outB, u16* __restrict__ outB2,
        const float* __restrict__ bias, const float* __restrict__ resid,
        const float* __restrict__ ts, const float* __restrict__ tc){
    int tid = threadIdx.x;
    int lane = tid & 63, wid = tid >> 6;
    int wm = wid >> 1, wn = wid & 1;
    int n0 = blockIdx.x*128 + wn*64;
    int m0 = blockIdx.y*128 + wm*64;
    int lr = lane & 15, lk = (lane >> 4) * 8;

    f32x4 acc[4][4];
    #pragma unroll
    for (int i=0;i<4;i++)
        #pragma unroll
        for (int j=0;j<4;j++) acc[i][j] = (f32x4){0.f,0.f,0.f,0.f};

    const u16* Ap = A + (size_t)(m0 + lr)*K + lk;
    const u16* Bp = B + (size_t)(n0 + lr)*K + lk;

    #pragma unroll 2
    for (int kc = 0; kc < K; kc += 32){
        short8 af[4], bf[4];
        #pragma unroll
        for (int i=0;i<4;i++) af[i] = *(const short8*)(Ap + (size_t)i*16*K + kc);
        #pragma unroll
        for (int i=0;i<4;i++) bf[i] = *(const short8*)(Bp + (size_t)i*16*K + kc);
        #pragma unroll
        for (int mi=0;mi<4;mi++)
            #pragma unroll
            for (int ni=0;ni<4;ni++)
                acc[mi][ni] = __builtin_amdgcn_mfma_f32_16x16x32_bf16(af[mi], bf[ni], acc[mi][ni], 0,0,0);
    }

    #pragma unroll
    for (int mi=0;mi<4;mi++){
        int mb = m0 + mi*16 + (lane>>4)*4;
        #pragma unroll
        for (int ni=0;ni<4;ni++){
            int n = n0 + ni*16 + lr;
            if (MODE == 0){
                #pragma unroll
                for (int r=0;r<4;r++){
                    int m = mb + r;
                    float v = acc[mi][ni][r];
                    if (bias)  v += bias[m];
                    size_t idx = (size_t)m*PP + n;
                    if (resid) v += resid[idx];
                    outF[idx] = v;
                }
            } else if (MODE == 1){
                int ph = n / 192, pw = n - ph*192;
                size_t ppos = (size_t)(ph+1)*PWP + (pw+1);
                ushort4 st;
                st.x = f2b(acc[mi][ni][0] + bias[mb]);
                st.y = f2b(acc[mi][ni][1] + bias[mb+1]);
                st.z = f2b(acc[mi][ni][2] + bias[mb+2]);
                st.w = f2b(acc[mi][ni][3] + bias[mb+3]);
                *(ushort4*)(outB + ppos*512 + mb) = st;
            } else { // MODE 3 / 4 : rope fused
                int d = n & 63, j = d & 31;
                int nb6 = n >> 6;
                #pragma unroll
                for (int r=0;r<4;r++){
                    int m = mb + r;
                    float a = acc[mi][ni][r];
                    if (MODE == 4 && m >= 512){
                        outB2[(size_t)(m-512)*PP + n] = f2b(a);
                    } else {
                        int pp = (m & 63)*576 + nb6;
                        int h = pp / 192, w = pp - h*192;
                        int tix = (j < 16) ? (h*16 + j) : (w*16 + (j-16));
                        float sv = ts[tix], cv = tc[tix];
                        float sg = (d & 1) ? sv : -sv;
                        float val;
                        if (MODE == 3) val = a * (cv + sg) * 0.125f;
                        else           val = a * (1.f + sg) + cv;
                        outB[(size_t)m*PP + n] = f2b(val);
                    }
                }
            }
        }
    }
}

// ---------------- V window transpose: vbf flat [row][64] -> vt [win][d][j] --
__global__ __launch_bounds__(256) void k_vt(const u16* __restrict__ v, u16* __restrict__ vt){
    __shared__ u32 TI[64][132];
    int tid = threadIdx.x;
    size_t wbase = (size_t)blockIdx.x*16384;
    int jp = tid >> 1, half = tid & 1;
    const u16* r0 = v + wbase + (size_t)(2*jp)*64 + half*32;
    const u16* r1 = r0 + 64;
    #pragma unroll
    for (int t=0; t<4; t++){
        short8 a = *(const short8*)(r0 + t*8);
        short8 b = *(const short8*)(r1 + t*8);
        #pragma unroll
        for (int e=0; e<8; e++){
            int d = half*32 + t*8 + e;
            TI[d][jp] = (u32)(u16)a[e] | ((u32)(u16)b[e] << 16);
        }
    }
    __syncthreads();
    int d = tid >> 2, q4 = tid & 3;
    u32* o32 = (u32*)(vt + wbase) + d*128 + q4*32;
    #pragma unroll
    for (int t=0; t<32; t++) o32[t] = TI[d][q4*32 + t];
}

// ---------------- MFMA flash window-attention -----------------------------
__global__ __launch_bounds__(256,2) void k_attn(const u16* __restrict__ q16, const u16* __restrict__ k16,
                                                const u16* __restrict__ vt, u16* __restrict__ ob){
    __shared__ u16 Pt[4][64][80];
    __shared__ float bc[4][64];
    int tid = threadIdx.x;
    int wave = tid >> 6, lane = tid & 63;
    int lr = lane & 15, g = lane >> 4;
    int lk = g*8;
    size_t wbase = (size_t)blockIdx.x * 16384;

    short8 bq[2][4];
    #pragma unroll
    for (int kh=0; kh<2; kh++)
        #pragma unroll
        for (int ni=0; ni<4; ni++)
            bq[kh][ni] = *(const short8*)(q16 + wbase + (size_t)(wave*64 + ni*16 + lr)*64 + kh*32 + lk);

    f32x4 oAcc[4][4];
    #pragma unroll
    for (int mi=0;mi<4;mi++)
        #pragma unroll
        for (int ni=0;ni<4;ni++) oAcc[mi][ni] = (f32x4){0.f,0.f,0.f,0.f};
    float mrun[4], lrun[4];
    #pragma unroll
    for (int ni=0;ni<4;ni++){ mrun[ni] = -1e30f; lrun[ni] = 0.f; }

    #pragma unroll 1
    for (int jc=0; jc<4; ++jc){
        f32x4 sAcc[4][4];
        #pragma unroll
        for (int mi=0;mi<4;mi++)
            #pragma unroll
            for (int ni=0;ni<4;ni++) sAcc[mi][ni] = (f32x4){0.f,0.f,0.f,0.f};
        #pragma unroll
        for (int kh=0; kh<2; kh++){
            short8 ak[4];
            #pragma unroll
            for (int mi=0;mi<4;mi++)
                ak[mi] = *(const short8*)(k16 + wbase + (size_t)(jc*64 + mi*16 + lr)*64 + kh*32 + lk);
            #pragma unroll
            for (int mi=0;mi<4;mi++)
                #pragma unroll
                for (int ni=0;ni<4;ni++)
                    sAcc[mi][ni] = __builtin_amdgcn_mfma_f32_16x16x32_bf16(ak[mi], bq[kh][ni], sAcc[mi][ni], 0,0,0);
        }
        float corr[4];
        #pragma unroll
        for (int ni=0;ni<4;ni++){
            float mx = sAcc[0][ni][0];
            #pragma unroll
            for (int mi=0;mi<4;mi++)
                #pragma unroll
                for (int r=0;r<4;r++) mx = fmaxf(mx, sAcc[mi][ni][r]);
            mx = fmaxf(mx, __shfl_xor(mx, 16));
            mx = fmaxf(mx, __shfl_xor(mx, 32));
            float mnew = fmaxf(mrun[ni], mx);
            corr[ni] = __expf(mrun[ni] - mnew);
            mrun[ni] = mnew;
        }
        #pragma unroll
        for (int ni=0;ni<4;ni++){
            float ls = 0.f;
            #pragma unroll
            for (int mi=0;mi<4;mi++)
                #pragma unroll
                for (int r=0;r<4;r++){
                    float p = __expf(sAcc[mi][ni][r] - mrun[ni]);
                    sAcc[mi][ni][r] = p;
                    ls += p;
                }
            ls += __shfl_xor(ls, 16);
            ls += __shfl_xor(ls, 32);
            lrun[ni] = lrun[ni]*corr[ni] + ls;
        }
        if (lane < 16){
            #pragma unroll
            for (int ni=0;ni<4;ni++) bc[wave][ni*16 + lr] = corr[ni];
        }
        #pragma unroll
        for (int mi=0;mi<4;mi++){
            float4 cf = *(float4*)&bc[wave][mi*16 + g*4];
            #pragma unroll
            for (int ni=0;ni<4;ni++){
                oAcc[mi][ni][0] *= cf.x; oAcc[mi][ni][1] *= cf.y;
                oAcc[mi][ni][2] *= cf.z; oAcc[mi][ni][3] *= cf.w;
            }
        }
        #pragma unroll
        for (int mi=0;mi<4;mi++)
            #pragma unroll
            for (int ni=0;ni<4;ni++){
                ushort4 pk;
                pk.x = f2b(sAcc[mi][ni][0]); pk.y = f2b(sAcc[mi][ni][1]);
                pk.z = f2b(sAcc[mi][ni][2]); pk.w = f2b(sAcc[mi][ni][3]);
                *(ushort4*)&Pt[wave][ni*16 + lr][mi*16 + g*4] = pk;
            }
        #pragma unroll
        for (int kh=0; kh<2; kh++){
            short8 pa[4], bv[4];
            #pragma unroll
            for (int mi=0;mi<4;mi++)
                pa[mi] = *(const short8*)&Pt[wave][mi*16 + lr][kh*32 + lk];
            #pragma unroll
            for (int ni=0;ni<4;ni++)
                bv[ni] = *(const short8*)(vt + wbase + (size_t)(ni*16 + lr)*256 + jc*64 + kh*32 + lk);
            #pragma unroll
            for (int mi=0;mi<4;mi++)
                #pragma unroll
                for (int ni=0;ni<4;ni++)
                    oAcc[mi][ni] = __builtin_amdgcn_mfma_f32_16x16x32_bf16(pa[mi], bv[ni], oAcc[mi][ni], 0,0,0);
        }
    }
    if (lane < 16){
        #pragma unroll
        for (int ni=0;ni<4;ni++) bc[wave][ni*16 + lr] = 1.f / lrun[ni];
    }
    #pragma unroll
    for (int mi=0;mi<4;mi++){
        float4 lf = *(float4*)&bc[wave][mi*16 + g*4];
        float lfa[4] = {lf.x, lf.y, lf.z, lf.w};
        #pragma unroll
        for (int ni=0;ni<4;ni++){
            #pragma unroll
            for (int r=0;r<4;r++){
                size_t idx = wbase + (size_t)(wave*64 + mi*16 + g*4 + r)*64 + ni*16 + lr;
                ob[idx] = f2b(oAcc[mi][ni][r] * lfa[r]);
            }
        }
    }
}

// ---------------- transpose: bf16 flat [512][PP] -> bf16 [PP][512] --------
__global__ __launch_bounds__(256) void k_tr(const u16* __restrict__ in, u16* __restrict__ out){
    __shared__ float T[64][65];
    int p0 = blockIdx.x*64, c0 = blockIdx.y*64;
    int tid = threadIdx.x;
    #pragma unroll
    for (int it=0; it<16; ++it){
        int e = tid + 256*it;
        int c = e >> 6, p = e & 63;
        T[c][p] = b2f(in[(size_t)(c0+c)*PP + p0 + p]);
    }
    __syncthreads();
    #pragma unroll
    for (int it=0; it<4; ++it){
        int e = tid + 256*it;
        int p = e >> 4, qd = e & 15;
        ushort4 st;
        st.x = f2b(T[qd*4+0][p]); st.y = f2b(T[qd*4+1][p]);
        st.z = f2b(T[qd*4+2][p]); st.w = f2b(T[qd*4+3][p]);
        *(ushort4*)(out + (size_t)(p0+p)*512 + c0 + qd*4) = st;
    }
}

// ---------------- conv3x3: LDS-staged halo tile, double-buffered ----------
// Wr bf16 [9][512 o][512 c]; Hb padded bf16 [194*194][512]; Gb bf16 [PP][512]
// block: h row x 128 o x 192 pos; LDS tile per 32-ch chunk: [3 ky][208 col][32 ch]
__global__ __launch_bounds__(256) void k_conv(const u16* __restrict__ Wr, const u16* __restrict__ Hb,
                                              const float* __restrict__ b2, u16* __restrict__ Gb){
    __shared__ u16 Hl[2][3*LCOLS*32];    // 2 x 39,936 B
    int tid = threadIdx.x;
    int lane = tid & 63, wid = tid >> 6;
    int wm = wid >> 1, wn = wid & 1;
    int h = blockIdx.x;
    int o0 = blockIdx.y*128 + wm*64;
    int lr = lane & 15, g = lane >> 4, lk = g*8;
    int colb = wn*96;

    f32x4 acc[4][6];
    #pragma unroll
    for (int i=0;i<4;i++)
        #pragma unroll
        for (int j=0;j<6;j++) acc[i][j] = (f32x4){0.f,0.f,0.f,0.f};

    const u16* Ap = Wr + (size_t)(o0 + lr)*512 + lk;
    int lpos = lane >> 2, lch = (lane & 3)*8;

    // stage one 32-channel chunk into buf: 39 segments of 16 positions, 10/wave
    #define STAGE(buf, c0) {                                                          \
        _Pragma("unroll")                                                             \
        for (int r2=0; r2<10; ++r2){                                                  \
            int i = wid + 4*r2; if (i > 38) i = 38;                                   \
            int ky = i/13, cs = i - ky*13;                                            \
            int col0 = cs*16;                                                         \
            const u16* src = Hb + ((size_t)(h+ky)*194 + col0 + lpos)*512 + (c0) + lch;\
            stage16(src, &Hl[buf][(ky*LCOLS + col0)*32]);                             \
        }                                                                             \
    }

    STAGE(0, 0)
    #pragma unroll 1
    for (int cc = 0; cc < 16; ++cc){
        int b = cc & 1;
        if (cc < 15){
            STAGE(b^1, (cc+1)*32)
            asm volatile("s_waitcnt vmcnt(10)" ::: "memory");
        } else {
            asm volatile("s_waitcnt vmcnt(0)" ::: "memory");
        }
        __builtin_amdgcn_s_barrier();
        asm volatile("" ::: "memory");

        #pragma unroll
        for (int t=0;t<9;t++){
            int ky = t/3, kx = t - ky*3;
            short8 af[4], bf[6];
            #pragma unroll
            for (int mi=0;mi<4;mi++)
                af[mi] = *(const short8*)(Ap + ((size_t)t*512 + mi*16)*512 + cc*32);
            #pragma unroll
            for (int nj=0;nj<6;nj++)
                bf[nj] = *(const short8*)&Hl[b][(ky*LCOLS + colb + nj*16 + lr + kx)*32 + lk];
            #pragma unroll
            for (int mi=0;mi<4;mi++)
                #pragma unroll
                for (int nj=0;nj<6;nj++)
                    acc[mi][nj] = __builtin_amdgcn_mfma_f32_16x16x32_bf16(af[mi], bf[nj], acc[mi][nj], 0,0,0);
        }
        asm volatile("" ::: "memory");
        __builtin_amdgcn_s_barrier();
    }
    #undef STAGE

    #pragma unroll
    for (int mi=0;mi<4;mi++){
        int ob = o0 + mi*16 + g*4;
        float b0 = b2[ob], b1v = b2[ob+1], b2v = b2[ob+2], b3v = b2[ob+3];
        #pragma unroll
        for (int nj=0;nj<6;nj++){
            int p = h*192 + colb + nj*16 + lr;
            float v[4] = {acc[mi][nj][0]+b0, acc[mi][nj][1]+b1v, acc[mi][nj][2]+b2v, acc[mi][nj][3]+b3v};
            ushort4 st;
            #pragma unroll
            for (int r=0;r<4;r++){
                float gg = v[r]*0.5f*(1.f + erff(v[r]*0.70710678118654752f));
                ((u16*)&st)[r] = f2b(gg);
            }
            *(ushort4*)(Gb + (size_t)p*512 + ob) = st;
        }
    }
}

// ---------------------------------------------------------------------------
extern "C" void kernel_launch(void* const* d_in, const int* in_sizes, int n_in,
                              void* d_out, int out_size, void* d_ws, size_t ws_size,
                              hipStream_t stream){
    const float* x     = (const float*)d_in[0];
    const float* ln1_g = (const float*)d_in[1];
    const float* ln1_b = (const float*)d_in[2];
    const float* wq    = (const float*)d_in[3];
    const float* wkv   = (const float*)d_in[4];
    const float* wo    = (const float*)d_in[5];
    const float* ln2_g = (const float*)d_in[6];
    const float* ln2_b = (const float*)d_in[7];
    const float* w1    = (const float*)d_in[8];
    const float* b1    = (const float*)d_in[9];
    const float* w2    = (const float*)d_in[10];
    const float* b2    = (const float*)d_in[11];
    const float* w3    = (const float*)d_in[12];
    const float* b3    = (const float*)d_in[13];

    float* xo = (float*)d_out;
    char* base = (char*)d_ws;

    u16*  R1   = (u16*)(base);                      //  37,748,736
    u16*  q16  = (u16*)(base + 37748736);           //  Hb overlays q16+k16 in LeFF
    u16*  Hb   = (u16*)(base + 37748736);
    u16*  k16  = (u16*)(base + 75497472);
    u16*  vbf  = (u16*)(base + 113246208);
    u16*  vt   = (u16*)(base + 150994944);
    u16*  Gb   = vt;
    u16*  wqb  = (u16*)(base + 188743680);
    u16*  wkvb = (u16*)(base + 189005824);
    u16*  wob  = (u16*)(base + 189530112);
    u16*  w1b  = (u16*)(base + 189792256);
    u16*  w3b  = (u16*)(base + 190054400);
    u16*  w2r  = (u16*)(base + 190316544);
    float* tsb = (float*)(base + 199753728);
    float* tcb = (float*)(base + 199766016);

    (void)hipMemcpyAsync(xo, x, sizeof(float)*(size_t)128*PP, hipMemcpyDeviceToDevice, stream);
    k_rotab<<<12, 256, 0, stream>>>(tsb, tcb);
    k_cast<<<512,  256, 0, stream>>>(wq,  wqb,  131072);
    k_cast<<<1024, 256, 0, stream>>>(wkv, wkvb, 262144);
    k_cast<<<512,  256, 0, stream>>>(wo,  wob,  131072);
    k_cast<<<512,  256, 0, stream>>>(w1,  w1b,  131072);
    k_cast<<<512,  256, 0, stream>>>(w3,  w3b,  131072);
    for (int l=0;l<2;l++)
        k_w2re<<<9216, 256, 0, stream>>>(w2 + (size_t)l*2359296, w2r + (size_t)l*2359296);

    for (int l = 0; l < 2; ++l){
        // ---- attention branch ----
        k_ln<<<144, 256, 0, stream>>>(xo, ln1_g + l*128, ln1_b + l*128, (u32*)R1);
        k_mmbt<128,3><<<dim3(288,4), 256, 0, stream>>>(wqb + (size_t)l*65536, R1,
                nullptr, q16, nullptr, nullptr, nullptr, tsb, tcb);
        k_mmbt<128,4><<<dim3(288,8), 256, 0, stream>>>(wkvb + (size_t)l*131072, R1,
                nullptr, k16, vbf, nullptr, nullptr, tsb, tcb);
        k_vt<<<1152, 256, 0, stream>>>(vbf, vt);
        k_attn<<<1152, 256, 0, stream>>>(q16, k16, vt, vbf);
        k_tr<<<dim3(576,8), 256, 0, stream>>>(vbf, R1);
        k_mmbt<512,0><<<dim3(288,1), 256, 0, stream>>>(wob + (size_t)l*65536, R1,
                xo, nullptr, nullptr, nullptr, xo, nullptr, nullptr);
        // ---- LeFF branch ----
        k_ln<<<144, 256, 0, stream>>>(xo, ln2_g + l*128, ln2_b + l*128, (u32*)R1);
        (void)hipMemsetAsync(Hb, 0, HB_BYTES, stream);
        k_mmbt<128,1><<<dim3(288,4), 256, 0, stream>>>(w1b + (size_t)l*65536, R1,
                nullptr, Hb, nullptr, b1 + l*512, nullptr, nullptr, nullptr);
        k_conv<<<dim3(192,4), 256, 0, stream>>>(w2r + (size_t)l*2359296, Hb, b2 + l*512, Gb);
        k_mmbt<512,0><<<dim3(288,1), 256, 0, stream>>>(w3b + (size_t)l*65536, Gb,
                xo, nullptr, nullptr, b3 + l*128, xo, nullptr, nullptr);
    }
}

// Round 8
// 1444.885 us; speedup vs baseline: 17.5249x; 1.0308x over previous
//
#include <hip/hip_runtime.h>
#include <hip/hip_bf16.h>
#include <math.h>

#define PP   36864            // 192*192
#define PWP  194              // padded width
#define HB_BYTES ((size_t)194*194*512*2)
#define LCOLS 208             // staged cols per ky row (16-aligned, >=194)

typedef __attribute__((ext_vector_type(8))) short short8;
typedef float f32x4 __attribute__((ext_vector_type(4)));
typedef unsigned short u16;
typedef unsigned int   u32;

constexpr float LN_EPS = 1e-5f;
constexpr float PI_F   = 3.14159265358979323846f;

__device__ __forceinline__ u16 f2b(float x){
    __hip_bfloat16 h = __float2bfloat16(x);
    return __builtin_bit_cast(u16, h);
}
__device__ __forceinline__ float b2f(u16 u){
    u32 v = ((u32)u) << 16;
    return __builtin_bit_cast(float, v);
}
__device__ __forceinline__ void stage16(const u16* g, u16* l){
    __builtin_amdgcn_global_load_lds((const __attribute__((address_space(1))) void*)g,
                                     (__attribute__((address_space(3))) void*)l, 16, 0, 0);
}

// ---------------- rotary tables ------------------------------------------
__global__ __launch_bounds__(256) void k_rotab(float* __restrict__ ts, float* __restrict__ tc){
    int i = blockIdx.x*256 + threadIdx.x;
    if (i >= 192*16) return;
    int h = i >> 4, j = i & 15;
    float lin = -1.f + 2.f*h/191.f;
    float sc  = 1.f + 4.f*j/15.f;
    float a   = lin*sc*PI_F;
    ts[i] = sinf(a); tc[i] = cosf(a);
}

// ---------------- fp32 -> bf16 cast --------------------------------------
__global__ __launch_bounds__(256) void k_cast(const float* __restrict__ s, u16* __restrict__ d, int n){
    int i = blockIdx.x*256 + threadIdx.x;
    if (i < n) d[i] = f2b(s[i]);
}

// ---------------- w2 reorder: [o][c][t] -> [t][o][c] bf16 ----------------
__global__ __launch_bounds__(256) void k_w2re(const float* __restrict__ s, u16* __restrict__ d){
    int i = blockIdx.x*256 + threadIdx.x;
    if (i >= 9*512*512) return;
    int t = i >> 18;
    int rem = i & 262143;       // o*512 + c
    d[i] = f2b(s[(size_t)rem*9 + t]);
}

// ---------------- channel LayerNorm -> position-major bf16 [p][128] ------
__global__ __launch_bounds__(256) void k_ln(const float* __restrict__ x, const float* __restrict__ g,
                                            const float* __restrict__ b, u32* __restrict__ xt){
    int p = blockIdx.x*256 + threadIdx.x;
    float s = 0.f, s2 = 0.f;
    for (int c = 0; c < 128; ++c){ float v = x[(size_t)c*PP + p]; s += v; s2 += v*v; }
    float mu  = s * (1.f/128.f);
    float var = s2 * (1.f/128.f) - mu*mu;
    float inv = rsqrtf(var + LN_EPS);
    for (int c = 0; c < 64; ++c){
        float v0 = (x[(size_t)(2*c)*PP + p]   - mu)*inv*g[2*c]   + b[2*c];
        float v1 = (x[(size_t)(2*c+1)*PP + p] - mu)*inv*g[2*c+1] + b[2*c+1];
        xt[(size_t)p*64 + c] = (u32)f2b(v0) | ((u32)f2b(v1) << 16);
    }
}

// ---------------- MFMA GEMM: Out[m][n] = sum_k A[m][k] * B[n][k] ----------
// A bf16 [M][K] row-major, B bf16 [N=PP][K] row-major. 128x128 block, 4 waves.
// MODE 0: fp32 out [m][PP] (+bias,+resid)
// MODE 1: bf16 out to padded Hb [(ph+1)*194+pw+1][512] + bias
// MODE 3: rope-q: outB u16 flat[m*PP+n] = bf16( a*(cos+-sin)*0.125 )
// MODE 4: m<512: rope-k -> outB; m>=512: plain bf16 -> outB2[(m-512)*PP+n]
template<int K, int MODE>
__global__ __launch_bounds__(256) void k_mmbt(const u16* __restrict__ A, const u16* __restrict__ B,
        float* __restrict__ outF, u16* __restrict__ outB, u16* __restrict__ outB2,
        const float* __restrict__ bias, const float* __restrict__ resid,
        const float* __restrict__ ts, const float* __restrict__ tc){
    int tid = threadIdx.x;
    int lane = tid & 63, wid = tid >> 6;
    int wm = wid >> 1, wn = wid & 1;
    int n0 = blockIdx.x*128 + wn*64;
    int m0 = blockIdx.y*128 + wm*64;
    int lr = lane & 15, lk = (lane >> 4) * 8;

    f32x4 acc[4][4];
    #pragma unroll
    for (int i=0;i<4;i++)
        #pragma unroll
        for (int j=0;j<4;j++) acc[i][j] = (f32x4){0.f,0.f,0.f,0.f};

    const u16* Ap = A + (size_t)(m0 + lr)*K + lk;
    const u16* Bp = B + (size_t)(n0 + lr)*K + lk;

    #pragma unroll 2
    for (int kc = 0; kc < K; kc += 32){
        short8 af[4], bf[4];
        #pragma unroll
        for (int i=0;i<4;i++) af[i] = *(const short8*)(Ap + (size_t)i*16*K + kc);
        #pragma unroll
        for (int i=0;i<4;i++) bf[i] = *(const short8*)(Bp + (size_t)i*16*K + kc);
        #pragma unroll
        for (int mi=0;mi<4;mi++)
            #pragma unroll
            for (int ni=0;ni<4;ni++)
                acc[mi][ni] = __builtin_amdgcn_mfma_f32_16x16x32_bf16(af[mi], bf[ni], acc[mi][ni], 0,0,0);
    }

    #pragma unroll
    for (int mi=0;mi<4;mi++){
        int mb = m0 + mi*16 + (lane>>4)*4;
        #pragma unroll
        for (int ni=0;ni<4;ni++){
            int n = n0 + ni*16 + lr;
            if (MODE == 0){
                #pragma unroll
                for (int r=0;r<4;r++){
                    int m = mb + r;
                    float v = acc[mi][ni][r];
                    if (bias)  v += bias[m];
                    size_t idx = (size_t)m*PP + n;
                    if (resid) v += resid[idx];
                    outF[idx] = v;
                }
            } else if (MODE == 1){
                int ph = n / 192, pw = n - ph*192;
                size_t ppos = (size_t)(ph+1)*PWP + (pw+1);
                ushort4 st;
                st.x = f2b(acc[mi][ni][0] + bias[mb]);
                st.y = f2b(acc[mi][ni][1] + bias[mb+1]);
                st.z = f2b(acc[mi][ni][2] + bias[mb+2]);
                st.w = f2b(acc[mi][ni][3] + bias[mb+3]);
                *(ushort4*)(outB + ppos*512 + mb) = st;
            } else { // MODE 3 / 4 : rope fused
                int d = n & 63, j = d & 31;
                int nb6 = n >> 6;
                #pragma unroll
                for (int r=0;r<4;r++){
                    int m = mb + r;
                    float a = acc[mi][ni][r];
                    if (MODE == 4 && m >= 512){
                        outB2[(size_t)(m-512)*PP + n] = f2b(a);
                    } else {
                        int pp = (m & 63)*576 + nb6;
                        int h = pp / 192, w = pp - h*192;
                        int tix = (j < 16) ? (h*16 + j) : (w*16 + (j-16));
                        float sv = ts[tix], cv = tc[tix];
                        float sg = (d & 1) ? sv : -sv;
                        float val;
                        if (MODE == 3) val = a * (cv + sg) * 0.125f;
                        else           val = a * (1.f + sg) + cv;
                        outB[(size_t)m*PP + n] = f2b(val);
                    }
                }
            }
        }
    }
}

// ---------------- V window transpose: vbf flat [row][64] -> vt [win][d][j] --
__global__ __launch_bounds__(256) void k_vt(const u16* __restrict__ v, u16* __restrict__ vt){
    __shared__ u32 TI[64][132];
    int tid = threadIdx.x;
    size_t wbase = (size_t)blockIdx.x*16384;
    int jp = tid >> 1, half = tid & 1;
    const u16* r0 = v + wbase + (size_t)(2*jp)*64 + half*32;
    const u16* r1 = r0 + 64;
    #pragma unroll
    for (int t=0; t<4; t++){
        short8 a = *(const short8*)(r0 + t*8);
        short8 b = *(const short8*)(r1 + t*8);
        #pragma unroll
        for (int e=0; e<8; e++){
            int d = half*32 + t*8 + e;
            TI[d][jp] = (u32)(u16)a[e] | ((u32)(u16)b[e] << 16);
        }
    }
    __syncthreads();
    int d = tid >> 2, q4 = tid & 3;
    u32* o32 = (u32*)(vt + wbase) + d*128 + q4*32;
    #pragma unroll
    for (int t=0; t<32; t++) o32[t] = TI[d][q4*32 + t];
}

// ---------------- MFMA flash window-attention -----------------------------
__global__ __launch_bounds__(256,2) void k_attn(const u16* __restrict__ q16, const u16* __restrict__ k16,
                                                const u16* __restrict__ vt, u16* __restrict__ ob){
    __shared__ u16 Pt[4][64][80];
    __shared__ float bc[4][64];
    int tid = threadIdx.x;
    int wave = tid >> 6, lane = tid & 63;
    int lr = lane & 15, g = lane >> 4;
    int lk = g*8;
    size_t wbase = (size_t)blockIdx.x * 16384;

    short8 bq[2][4];
    #pragma unroll
    for (int kh=0; kh<2; kh++)
        #pragma unroll
        for (int ni=0; ni<4; ni++)
            bq[kh][ni] = *(const short8*)(q16 + wbase + (size_t)(wave*64 + ni*16 + lr)*64 + kh*32 + lk);

    f32x4 oAcc[4][4];
    #pragma unroll
    for (int mi=0;mi<4;mi++)
        #pragma unroll
        for (int ni=0;ni<4;ni++) oAcc[mi][ni] = (f32x4){0.f,0.f,0.f,0.f};
    float mrun[4], lrun[4];
    #pragma unroll
    for (int ni=0;ni<4;ni++){ mrun[ni] = -1e30f; lrun[ni] = 0.f; }

    #pragma unroll 1
    for (int jc=0; jc<4; ++jc){
        f32x4 sAcc[4][4];
        #pragma unroll
        for (int mi=0;mi<4;mi++)
            #pragma unroll
            for (int ni=0;ni<4;ni++) sAcc[mi][ni] = (f32x4){0.f,0.f,0.f,0.f};
        #pragma unroll
        for (int kh=0; kh<2; kh++){
            short8 ak[4];
            #pragma unroll
            for (int mi=0;mi<4;mi++)
                ak[mi] = *(const short8*)(k16 + wbase + (size_t)(jc*64 + mi*16 + lr)*64 + kh*32 + lk);
            #pragma unroll
            for (int mi=0;mi<4;mi++)
                #pragma unroll
                for (int ni=0;ni<4;ni++)
                    sAcc[mi][ni] = __builtin_amdgcn_mfma_f32_16x16x32_bf16(ak[mi], bq[kh][ni], sAcc[mi][ni], 0,0,0);
        }
        float corr[4];
        #pragma unroll
        for (int ni=0;ni<4;ni++){
            float mx = sAcc[0][ni][0];
            #pragma unroll
            for (int mi=0;mi<4;mi++)
                #pragma unroll
                for (int r=0;r<4;r++) mx = fmaxf(mx, sAcc[mi][ni][r]);
            mx = fmaxf(mx, __shfl_xor(mx, 16));
            mx = fmaxf(mx, __shfl_xor(mx, 32));
            float mnew = fmaxf(mrun[ni], mx);
            corr[ni] = __expf(mrun[ni] - mnew);
            mrun[ni] = mnew;
        }
        #pragma unroll
        for (int ni=0;ni<4;ni++){
            float ls = 0.f;
            #pragma unroll
            for (int mi=0;mi<4;mi++)
                #pragma unroll
                for (int r=0;r<4;r++){
                    float p = __expf(sAcc[mi][ni][r] - mrun[ni]);
                    sAcc[mi][ni][r] = p;
                    ls += p;
                }
            ls += __shfl_xor(ls, 16);
            ls += __shfl_xor(ls, 32);
            lrun[ni] = lrun[ni]*corr[ni] + ls;
        }
        if (lane < 16){
            #pragma unroll
            for (int ni=0;ni<4;ni++) bc[wave][ni*16 + lr] = corr[ni];
        }
        #pragma unroll
        for (int mi=0;mi<4;mi++){
            float4 cf = *(float4*)&bc[wave][mi*16 + g*4];
            #pragma unroll
            for (int ni=0;ni<4;ni++){
                oAcc[mi][ni][0] *= cf.x; oAcc[mi][ni][1] *= cf.y;
                oAcc[mi][ni][2] *= cf.z; oAcc[mi][ni][3] *= cf.w;
            }
        }
        #pragma unroll
        for (int mi=0;mi<4;mi++)
            #pragma unroll
            for (int ni=0;ni<4;ni++){
                ushort4 pk;
                pk.x = f2b(sAcc[mi][ni][0]); pk.y = f2b(sAcc[mi][ni][1]);
                pk.z = f2b(sAcc[mi][ni][2]); pk.w = f2b(sAcc[mi][ni][3]);
                *(ushort4*)&Pt[wave][ni*16 + lr][mi*16 + g*4] = pk;
            }
        #pragma unroll
        for (int kh=0; kh<2; kh++){
            short8 pa[4], bv[4];
            #pragma unroll
            for (int mi=0;mi<4;mi++)
                pa[mi] = *(const short8*)&Pt[wave][mi*16 + lr][kh*32 + lk];
            #pragma unroll
            for (int ni=0;ni<4;ni++)
                bv[ni] = *(const short8*)(vt + wbase + (size_t)(ni*16 + lr)*256 + jc*64 + kh*32 + lk);
            #pragma unroll
            for (int mi=0;mi<4;mi++)
                #pragma unroll
                for (int ni=0;ni<4;ni++)
                    oAcc[mi][ni] = __builtin_amdgcn_mfma_f32_16x16x32_bf16(pa[mi], bv[ni], oAcc[mi][ni], 0,0,0);
        }
    }
    if (lane < 16){
        #pragma unroll
        for (int ni=0;ni<4;ni++) bc[wave][ni*16 + lr] = 1.f / lrun[ni];
    }
    #pragma unroll
    for (int mi=0;mi<4;mi++){
        float4 lf = *(float4*)&bc[wave][mi*16 + g*4];
        float lfa[4] = {lf.x, lf.y, lf.z, lf.w};
        #pragma unroll
        for (int ni=0;ni<4;ni++){
            #pragma unroll
            for (int r=0;r<4;r++){
                size_t idx = wbase + (size_t)(wave*64 + mi*16 + g*4 + r)*64 + ni*16 + lr;
                ob[idx] = f2b(oAcc[mi][ni][r] * lfa[r]);
            }
        }
    }
}

// ---------------- transpose: bf16 flat [512][PP] -> bf16 [PP][512] --------
__global__ __launch_bounds__(256) void k_tr(const u16* __restrict__ in, u16* __restrict__ out){
    __shared__ float T[64][65];
    int p0 = blockIdx.x*64, c0 = blockIdx.y*64;
    int tid = threadIdx.x;
    #pragma unroll
    for (int it=0; it<16; ++it){
        int e = tid + 256*it;
        int c = e >> 6, p = e & 63;
        T[c][p] = b2f(in[(size_t)(c0+c)*PP + p0 + p]);
    }
    __syncthreads();
    #pragma unroll
    for (int it=0; it<4; ++it){
        int e = tid + 256*it;
        int p = e >> 4, qd = e & 15;
        ushort4 st;
        st.x = f2b(T[qd*4+0][p]); st.y = f2b(T[qd*4+1][p]);
        st.z = f2b(T[qd*4+2][p]); st.w = f2b(T[qd*4+3][p]);
        *(ushort4*)(out + (size_t)(p0+p)*512 + c0 + qd*4) = st;
    }
}

// ---------------- conv3x3: LDS-staged halo tile, swizzled, dbuf -----------
// Wr bf16 [9][512 o][512 c]; Hb padded bf16 [194*194][512]; Gb bf16 [PP][512]
// grid (4 o-chunks, 192 h): same-h blocks adjacent for L2 halo reuse.
// LDS [3 ky][208 col][32 ch], 16B-slot swizzle: slot_g = g ^ ((col>>1)&3).
__global__ __launch_bounds__(256) void k_conv(const u16* __restrict__ Wr, const u16* __restrict__ Hb,
                                              const float* __restrict__ b2, u16* __restrict__ Gb){
    __shared__ u16 Hl[2][3*LCOLS*32];    // 2 x 39,936 B
    int tid = threadIdx.x;
    int lane = tid & 63, wid = tid >> 6;
    int wm = wid >> 1, wn = wid & 1;
    int h = blockIdx.y;
    int o0 = blockIdx.x*128 + wm*64;
    int lr = lane & 15, g = lane >> 4;
    int lk = g*8;
    int colb = wn*96;

    f32x4 acc[4][6];
    #pragma unroll
    for (int i=0;i<4;i++)
        #pragma unroll
        for (int j=0;j<6;j++) acc[i][j] = (f32x4){0.f,0.f,0.f,0.f};

    const u16* Ap = Wr + (size_t)(o0 + lr)*512 + lk;
    // stage source swizzle: lane -> (pos lane>>2, ch-group (lane&3)^((lane>>3)&3))
    int lpos = lane >> 2;
    int lch  = (((lane & 3) ^ ((lane >> 3) & 3)) * 8);

    #define STAGE(buf, c0) {                                                          \
        _Pragma("unroll")                                                             \
        for (int r2=0; r2<10; ++r2){                                                  \
            int i = wid + 4*r2; if (i > 38) i = 38;                                   \
            int ky = i/13, cs = i - ky*13;                                            \
            int col0 = cs*16;                                                         \
            const u16* src = Hb + ((size_t)(h+ky)*194 + col0 + lpos)*512 + (c0) + lch;\
            stage16(src, &Hl[buf][(ky*LCOLS + col0)*32]);                             \
        }                                                                             \
    }

    STAGE(0, 0)
    #pragma unroll 1
    for (int cc = 0; cc < 16; ++cc){
        int b = cc & 1;
        if (cc < 15){
            STAGE(b^1, (cc+1)*32)
            asm volatile("s_waitcnt vmcnt(10)" ::: "memory");
        } else {
            asm volatile("s_waitcnt vmcnt(0)" ::: "memory");
        }
        __builtin_amdgcn_s_barrier();
        asm volatile("" ::: "memory");

        #pragma unroll
        for (int t=0;t<9;t++){
            int ky = t/3, kx = t - ky*3;
            short8 af[4], bf[6];
            #pragma unroll
            for (int mi=0;mi<4;mi++)
                af[mi] = *(const short8*)(Ap + ((size_t)t*512 + mi*16)*512 + cc*32);
            #pragma unroll
            for (int nj=0;nj<6;nj++){
                int col2 = colb + nj*16 + lr + kx;
                bf[nj] = *(const short8*)&Hl[b][(ky*LCOLS + col2)*32 + ((g ^ ((col2>>1)&3))*8)];
            }
            #pragma unroll
            for (int mi=0;mi<4;mi++)
                #pragma unroll
                for (int nj=0;nj<6;nj++)
                    acc[mi][nj] = __builtin_amdgcn_mfma_f32_16x16x32_bf16(af[mi], bf[nj], acc[mi][nj], 0,0,0);
        }
        asm volatile("" ::: "memory");
        __builtin_amdgcn_s_barrier();
    }
    #undef STAGE

    #pragma unroll
    for (int mi=0;mi<4;mi++){
        int ob = o0 + mi*16 + g*4;
        float b0 = b2[ob], b1v = b2[ob+1], b2v = b2[ob+2], b3v = b2[ob+3];
        #pragma unroll
        for (int nj=0;nj<6;nj++){
            int p = h*192 + colb + nj*16 + lr;
            float v[4] = {acc[mi][nj][0]+b0, acc[mi][nj][1]+b1v, acc[mi][nj][2]+b2v, acc[mi][nj][3]+b3v};
            ushort4 st;
            #pragma unroll
            for (int r=0;r<4;r++){
                float gg = v[r]*0.5f*(1.f + erff(v[r]*0.70710678118654752f));
                ((u16*)&st)[r] = f2b(gg);
            }
            *(ushort4*)(Gb + (size_t)p*512 + ob) = st;
        }
    }
}

// ---------------------------------------------------------------------------
extern "C" void kernel_launch(void* const* d_in, const int* in_sizes, int n_in,
                              void* d_out, int out_size, void* d_ws, size_t ws_size,
                              hipStream_t stream){
    const float* x     = (const float*)d_in[0];
    const float* ln1_g = (const float*)d_in[1];
    const float* ln1_b = (const float*)d_in[2];
    const float* wq    = (const float*)d_in[3];
    const float* wkv   = (const float*)d_in[4];
    const float* wo    = (const float*)d_in[5];
    const float* ln2_g = (const float*)d_in[6];
    const float* ln2_b = (const float*)d_in[7];
    const float* w1    = (const float*)d_in[8];
    const float* b1    = (const float*)d_in[9];
    const float* w2    = (const float*)d_in[10];
    const float* b2    = (const float*)d_in[11];
    const float* w3    = (const float*)d_in[12];
    const float* b3    = (const float*)d_in[13];

    float* xo = (float*)d_out;
    char* base = (char*)d_ws;

    u16*  R1   = (u16*)(base);                      //  37,748,736
    u16*  q16  = (u16*)(base + 37748736);           //  Hb overlays q16+k16 in LeFF
    u16*  Hb   = (u16*)(base + 37748736);
    u16*  k16  = (u16*)(base + 75497472);
    u16*  vbf  = (u16*)(base + 113246208);
    u16*  vt   = (u16*)(base + 150994944);
    u16*  Gb   = vt;
    u16*  wqb  = (u16*)(base + 188743680);
    u16*  wkvb = (u16*)(base + 189005824);
    u16*  wob  = (u16*)(base + 189530112);
    u16*  w1b  = (u16*)(base + 189792256);
    u16*  w3b  = (u16*)(base + 190054400);
    u16*  w2r  = (u16*)(base + 190316544);
    float* tsb = (float*)(base + 199753728);
    float* tcb = (float*)(base + 199766016);

    (void)hipMemcpyAsync(xo, x, sizeof(float)*(size_t)128*PP, hipMemcpyDeviceToDevice, stream);
    k_rotab<<<12, 256, 0, stream>>>(tsb, tcb);
    k_cast<<<512,  256, 0, stream>>>(wq,  wqb,  131072);
    k_cast<<<1024, 256, 0, stream>>>(wkv, wkvb, 262144);
    k_cast<<<512,  256, 0, stream>>>(wo,  wob,  131072);
    k_cast<<<512,  256, 0, stream>>>(w1,  w1b,  131072);
    k_cast<<<512,  256, 0, stream>>>(w3,  w3b,  131072);
    for (int l=0;l<2;l++)
        k_w2re<<<9216, 256, 0, stream>>>(w2 + (size_t)l*2359296, w2r + (size_t)l*2359296);

    for (int l = 0; l < 2; ++l){
        // ---- attention branch ----
        k_ln<<<144, 256, 0, stream>>>(xo, ln1_g + l*128, ln1_b + l*128, (u32*)R1);
        k_mmbt<128,3><<<dim3(288,4), 256, 0, stream>>>(wqb + (size_t)l*65536, R1,
                nullptr, q16, nullptr, nullptr, nullptr, tsb, tcb);
        k_mmbt<128,4><<<dim3(288,8), 256, 0, stream>>>(wkvb + (size_t)l*131072, R1,
                nullptr, k16, vbf, nullptr, nullptr, tsb, tcb);
        k_vt<<<1152, 256, 0, stream>>>(vbf, vt);
        k_attn<<<1152, 256, 0, stream>>>(q16, k16, vt, vbf);
        k_tr<<<dim3(576,8), 256, 0, stream>>>(vbf, R1);
        k_mmbt<512,0><<<dim3(288,1), 256, 0, stream>>>(wob + (size_t)l*65536, R1,
                xo, nullptr, nullptr, nullptr, xo, nullptr, nullptr);
        // ---- LeFF branch ----
        k_ln<<<144, 256, 0, stream>>>(xo, ln2_g + l*128, ln2_b + l*128, (u32*)R1);
        (void)hipMemsetAsync(Hb, 0, HB_BYTES, stream);
        k_mmbt<128,1><<<dim3(288,4), 256, 0, stream>>>(w1b + (size_t)l*65536, R1,
                nullptr, Hb, nullptr, b1 + l*512, nullptr, nullptr, nullptr);
        k_conv<<<dim3(4,192), 256, 0, stream>>>(w2r + (size_t)l*2359296, Hb, b2 + l*512, Gb);
        k_mmbt<512,0><<<dim3(288,1), 256, 0, stream>>>(w3b + (size_t)l*65536, Gb,
                xo, nullptr, nullptr, b3 + l*128, xo, nullptr, nullptr);
    }
}